// Round 3
// baseline (5996.541 us; speedup 1.0000x reference)
//
#include <hip/hip_runtime.h>
#include <cstdint>
#include <cstddef>

// ---------------------------------------------------------------------------
// HAN forward on gfx950. Float input dtype (fp32 vs bf16) is UNKNOWN at build
// time -> runtime probe kernel writes a mode flag into d_ws; all float-input
// reads and the output write branch on it (wave-uniform). Internals fp32;
// MFMA inputs bf16 (converted at staging) or hi+lo bf16 split (GRU h).
// Word-level pipeline phased over sentence chunks nb chosen from ws_size.
// ---------------------------------------------------------------------------

typedef __attribute__((ext_vector_type(8))) short bf16x8;   // 8 bf16 = 4 VGPR
typedef __attribute__((ext_vector_type(4))) float f32x4;

__device__ __forceinline__ float bfraw2f(unsigned int u16) {
    unsigned int x = u16 << 16; float f; __builtin_memcpy(&f, &x, 4); return f;
}
__device__ __forceinline__ unsigned short f2bfraw(float f) {  // RNE
    unsigned int u; __builtin_memcpy(&u, &f, 4);
    unsigned int r = u + 0x7fffu + ((u >> 16) & 1u);
    return (unsigned short)(r >> 16);
}
__device__ __forceinline__ unsigned short f2h(float f) {
    _Float16 h = (_Float16)f; unsigned short u; __builtin_memcpy(&u, &h, 2); return u;
}
__device__ __forceinline__ float h2f(unsigned short u) {
    _Float16 h; __builtin_memcpy(&h, &u, 2); return (float)h;
}
__device__ __forceinline__ float bflo(unsigned int p) {
    unsigned int x = p << 16; float f; __builtin_memcpy(&f, &x, 4); return f;
}
__device__ __forceinline__ float bfhi(unsigned int p) {
    unsigned int x = p & 0xffff0000u; float f; __builtin_memcpy(&f, &x, 4); return f;
}
__device__ __forceinline__ float fast_sigmoid(float x) { return 1.f / (1.f + __expf(-x)); }
__device__ __forceinline__ float fast_tanh(float x) {
    x = fminf(fmaxf(x, -30.f), 30.f);
    float e = __expf(2.f * x);
    return (e - 1.f) / (e + 1.f);
}
__device__ __forceinline__ float fin(float x) {           // NaN/inf scrubber
    return (x == x && fabsf(x) < 1e30f) ? x : 0.f;
}

// ---- dual-mode input adapters (m=1: bf16 u16 buffer, m=0: fp32 buffer) ----
__device__ __forceinline__ float ldsc(const void* p, size_t i, int m) {
    return m ? bfraw2f(((const unsigned short*)p)[i]) : ((const float*)p)[i];
}
__device__ __forceinline__ bf16x8 ld8bf(const void* p, size_t ei, int m) {
    if (m) return *(const bf16x8*)((const unsigned short*)p + ei);
    const float* f = (const float*)p + ei;
    f32x4 a = *(const f32x4*)f, b = *(const f32x4*)(f + 4);
    bf16x8 r;
    r[0] = (short)f2bfraw(a[0]); r[1] = (short)f2bfraw(a[1]);
    r[2] = (short)f2bfraw(a[2]); r[3] = (short)f2bfraw(a[3]);
    r[4] = (short)f2bfraw(b[0]); r[5] = (short)f2bfraw(b[1]);
    r[6] = (short)f2bfraw(b[2]); r[7] = (short)f2bfraw(b[3]);
    return r;
}
__device__ __forceinline__ void ld8f(const void* p, size_t ei, int m, float* o) {
    if (m) {
        uint4 wv = *(const uint4*)((const unsigned short*)p + ei);
        o[0] = bflo(wv.x); o[1] = bfhi(wv.x); o[2] = bflo(wv.y); o[3] = bfhi(wv.y);
        o[4] = bflo(wv.z); o[5] = bfhi(wv.z); o[6] = bflo(wv.w); o[7] = bfhi(wv.w);
    } else {
        const float* f = (const float*)p + ei;
        #pragma unroll
        for (int i = 0; i < 8; ++i) o[i] = f[i];
    }
}

// ---------------------------------------------------------------------------
// K0: dtype probe. w holds ~N(0,0.05) weights. If buffer is bf16, every u16
// decodes to |x|<=1. If fp32, low mantissa halves are ~uniform -> ~50% decode
// to |x|>1 or NaN. 512 words => error prob ~2^-256.
// ---------------------------------------------------------------------------
__global__ void k_probe(const unsigned short* __restrict__ w, int* __restrict__ flag) {
    if (threadIdx.x == 0) {
        int bad = 0;
        for (int i = 0; i < 512; ++i) {
            float v = bfraw2f(w[i]);
            if (!(fabsf(v) <= 1.0f)) bad++;   // NaN also lands here
        }
        flag[0] = (bad == 0) ? 1 : 0;         // 1 = bf16 mode, 0 = fp32 mode
    }
}

// ---------------------------------------------------------------------------
// K1: gathered word projection for a phase of nb sentences.
// xp[dir][t][bl][768] (fp16 internal), GEMM (64*nb x 512)@(512x1536),
// MFMA 16x16x32 bf16, BM=64 BN=256 BK=32, grid (nb, 6).
// ---------------------------------------------------------------------------
__global__ __launch_bounds__(256, 2) void k_xp_word(
    const void* __restrict__ embed_doc, const int* __restrict__ batch_doc,
    const void* __restrict__ wih_f, const void* __restrict__ wih_b,
    const void* __restrict__ bih_f, const void* __restrict__ bih_b,
    unsigned short* __restrict__ xp, int b0, int nb, const int* __restrict__ modep)
{
    __shared__ unsigned short As[64][40];   // pitch 80B, 16B-aligned rows
    __shared__ unsigned short Bs[256][40];
    const int m = modep[0];
    const int bm = blockIdx.x, bc = blockIdx.y;
    const int tid = threadIdx.x;
    const int wave = tid >> 6, lane = tid & 63, lm = lane & 15, q = lane >> 4;
    const int arow = tid >> 2, akoff = (tid & 3) * 8;
    const int r = bm * 64 + arow;           // phase-local row = t*nb + bl
    const int tt = r / nb, bl = r - tt * nb;
    const size_t aei = (size_t)batch_doc[(b0 + bl) * 64 + tt] * 512 + akoff;

    const void* bsrc[4];
    size_t bofs[4];
    #pragma unroll
    for (int ld = 0; ld < 4; ++ld) {
        int e = ld * 256 + tid;
        int n = e >> 2, koff = (e & 3) * 8;
        int gn = bc * 256 + n;
        bsrc[ld] = (gn < 768) ? wih_f : wih_b;
        bofs[ld] = (size_t)(gn < 768 ? gn : gn - 768) * 512 + koff;
    }

    const f32x4 fzero = {0.f, 0.f, 0.f, 0.f};
    f32x4 acc[4][4];
    #pragma unroll
    for (int i = 0; i < 4; ++i)
        #pragma unroll
        for (int j = 0; j < 4; ++j) acc[i][j] = fzero;

    for (int kt = 0; kt < 16; ++kt) {
        *(bf16x8*)&As[arow][akoff] = ld8bf(embed_doc, aei + kt * 32, m);
        #pragma unroll
        for (int ld = 0; ld < 4; ++ld) {
            int e = ld * 256 + tid;
            int n = e >> 2, koff = (e & 3) * 8;
            *(bf16x8*)&Bs[n][koff] = ld8bf(bsrc[ld], bofs[ld] + kt * 32, m);
        }
        __syncthreads();
        bf16x8 af[4], bv[4];
        #pragma unroll
        for (int mt = 0; mt < 4; ++mt) af[mt] = *(const bf16x8*)&As[mt * 16 + lm][q * 8];
        #pragma unroll
        for (int nt = 0; nt < 4; ++nt) bv[nt] = *(const bf16x8*)&Bs[wave * 64 + nt * 16 + lm][q * 8];
        #pragma unroll
        for (int mt = 0; mt < 4; ++mt)
            #pragma unroll
            for (int nt = 0; nt < 4; ++nt)
                acc[mt][nt] = __builtin_amdgcn_mfma_f32_16x16x32_bf16(af[mt], bv[nt], acc[mt][nt], 0, 0, 0);
        __syncthreads();
    }

    const size_t XPT = (size_t)64 * nb * 768;   // per-dir chunk
    #pragma unroll
    for (int nt = 0; nt < 4; ++nt) {
        const int cn = bc * 256 + wave * 64 + nt * 16 + lm;
        const int dirb = (cn >= 768);
        const int o = cn - dirb * 768;
        const float bias = ldsc(dirb ? bih_b : bih_f, o, m);
        #pragma unroll
        for (int mt = 0; mt < 4; ++mt) {
            #pragma unroll
            for (int j = 0; j < 4; ++j) {
                const int rr = bm * 64 + mt * 16 + q * 4 + j;   // D: row=q*4+j, col=lm
                xp[(dirb ? XPT : 0) + (size_t)rr * 768 + o] = f2h(acc[mt][nt][j] + bias);
            }
        }
    }
}

// ---------------------------------------------------------------------------
// K2: GRU recurrence, persistent per (dir, 16-row group). h in LDS (fp32 +
// hi/lo bf16 mirrors); g = Whh.(h_hi+h_lo) via MFMA, acc layout == gate layout.
// grid = 2*(NB/16). xp_fmt: 0 = fp32 (internal), 1 = fp16 (internal).
// ---------------------------------------------------------------------------
__global__ __launch_bounds__(256, 1) void k_gru(
    const void* __restrict__ xp, int xp_fmt,
    const void* __restrict__ whh_f, const void* __restrict__ whh_b,
    const void* __restrict__ bhh_f, const void* __restrict__ bhh_b,
    const int* __restrict__ lens, float* __restrict__ enc, int T, int NB,
    const int* __restrict__ modep)
{
    __shared__ float hS[16][260];
    __shared__ unsigned short hHi[16][264];   // pitch 528B, 16B-aligned rows
    __shared__ unsigned short hLo[16][264];
    __shared__ float bhhS[768];
    __shared__ int lensS[16];
    const int m = modep[0];
    const int tid = threadIdx.x;
    const int wave = tid >> 6, lane = tid & 63, lm = lane & 15, q = lane >> 4;
    const int dir = blockIdx.x & 1, sg = blockIdx.x >> 1;
    const int s0 = sg << 4;
    const void* whh = dir ? whh_b : whh_f;
    const void* bhh = dir ? bhh_b : bhh_f;
    const size_t dirOff = dir ? (size_t)T * NB * 768 : 0;

    for (int e = tid; e < 16 * 260; e += 256) (&hS[0][0])[e] = 0.f;
    for (int e = tid; e < 16 * 264; e += 256) { (&hHi[0][0])[e] = 0; (&hLo[0][0])[e] = 0; }
    for (int j = tid; j < 768; j += 256) bhhS[j] = ldsc(bhh, j, m);
    if (tid < 16) lensS[tid] = lens[s0 + tid];
    __syncthreads();

    const f32x4 fzero = {0.f, 0.f, 0.f, 0.f};
    for (int step = 0; step < T; ++step) {
        const int t = dir ? (T - 1 - step) : step;
        bf16x8 ahi[8], alo[8];
        #pragma unroll
        for (int ks = 0; ks < 8; ++ks) {
            ahi[ks] = *(const bf16x8*)&hHi[lm][ks * 32 + q * 8];
            alo[ks] = *(const bf16x8*)&hLo[lm][ks * 32 + q * 8];
        }
        __syncthreads();   // all h reads complete before anyone rewrites h

        f32x4 acc[12];     // reg 0/1/2 = r/z/n; wave owns cols [wave*64, +64)
        #pragma unroll
        for (int i = 0; i < 12; ++i) acc[i] = fzero;
        #pragma unroll
        for (int reg = 0; reg < 3; ++reg) {
            #pragma unroll
            for (int nt = 0; nt < 4; ++nt) {
                const size_t bbase =
                    ((size_t)(reg * 256 + wave * 64 + nt * 16 + lm)) * 256 + q * 8;
                const int ai = reg * 4 + nt;
                #pragma unroll
                for (int ks = 0; ks < 8; ++ks) {
                    bf16x8 bfr = ld8bf(whh, bbase + ks * 32, m);
                    acc[ai] = __builtin_amdgcn_mfma_f32_16x16x32_bf16(ahi[ks], bfr, acc[ai], 0, 0, 0);
                    acc[ai] = __builtin_amdgcn_mfma_f32_16x16x32_bf16(alo[ks], bfr, acc[ai], 0, 0, 0);
                }
            }
        }
        #pragma unroll
        for (int nt = 0; nt < 4; ++nt) {
            const int col = wave * 64 + nt * 16 + lm;
            const float br = bhhS[col], bz = bhhS[256 + col], bn = bhhS[512 + col];
            #pragma unroll
            for (int j = 0; j < 4; ++j) {
                const int s = q * 4 + j;                 // D row = sentence-in-group
                const size_t xb = dirOff + ((size_t)t * NB + s0 + s) * 768;
                float xr, xz, xn;
                if (xp_fmt == 1) {
                    const unsigned short* xpp = (const unsigned short*)xp + xb;
                    xr = h2f(xpp[col]); xz = h2f(xpp[256 + col]); xn = h2f(xpp[512 + col]);
                } else {
                    const float* xpp = (const float*)xp + xb;
                    xr = xpp[col]; xz = xpp[256 + col]; xn = xpp[512 + col];
                }
                const float rr = fast_sigmoid(xr + acc[nt][j] + br);
                const float zz = fast_sigmoid(xz + acc[nt + 4][j] + bz);
                const float nn = fast_tanh(xn + rr * (acc[nt + 8][j] + bn));
                const float hold = hS[s][col];
                float hnew = (1.f - zz) * nn + zz * hold;
                const bool v = (t < lensS[s]);
                hnew = v ? hnew : hold;
                hS[s][col] = hnew;
                const unsigned short uh = f2bfraw(hnew);
                hHi[s][col] = uh;
                hLo[s][col] = f2bfraw(hnew - bfraw2f(uh));
                enc[((size_t)t * NB + s0 + s) * 512 + (size_t)dir * 256 + col] = v ? hnew : 0.f;
            }
        }
        __syncthreads();   // h fully updated before next step's reads
    }
}

// ---------------------------------------------------------------------------
// K3: attention scores att[r] = sum_o tanh(enc[r].lin_w[o]+lin_b[o])*attw[o]
// GEMM (M x 512)@(512x512), BM=64, BN=512, fused tanh+reduce epilogue. grid=M/64.
// ---------------------------------------------------------------------------
__global__ __launch_bounds__(256, 1) void k_att(
    const float* __restrict__ enc, const void* __restrict__ lin_w,
    const void* __restrict__ lin_b, const void* __restrict__ attw,
    float* __restrict__ att_out, const int* __restrict__ modep)
{
    __shared__ unsigned short As[64][40];
    __shared__ unsigned short Bs[512][40];
    __shared__ float att_part[4][64];
    const int m = modep[0];
    const int bm = blockIdx.x;
    const int tid = threadIdx.x;
    const int wave = tid >> 6, lane = tid & 63, lm = lane & 15, q = lane >> 4;
    const int arow = tid >> 2, akoff = (tid & 3) * 8;
    const float* aptr = enc + (size_t)(bm * 64 + arow) * 512 + akoff;

    const f32x4 fzero = {0.f, 0.f, 0.f, 0.f};
    f32x4 acc[4][8];
    #pragma unroll
    for (int i = 0; i < 4; ++i)
        #pragma unroll
        for (int j = 0; j < 8; ++j) acc[i][j] = fzero;

    for (int kt = 0; kt < 16; ++kt) {
        f32x4 f0 = *(const f32x4*)(aptr + kt * 32);
        f32x4 f1 = *(const f32x4*)(aptr + kt * 32 + 4);
        bf16x8 cv;
        cv[0] = (short)f2bfraw(f0[0]); cv[1] = (short)f2bfraw(f0[1]);
        cv[2] = (short)f2bfraw(f0[2]); cv[3] = (short)f2bfraw(f0[3]);
        cv[4] = (short)f2bfraw(f1[0]); cv[5] = (short)f2bfraw(f1[1]);
        cv[6] = (short)f2bfraw(f1[2]); cv[7] = (short)f2bfraw(f1[3]);
        *(bf16x8*)&As[arow][akoff] = cv;
        #pragma unroll
        for (int ld = 0; ld < 8; ++ld) {
            int e = ld * 256 + tid;
            int n = e >> 2, koff = (e & 3) * 8;
            *(bf16x8*)&Bs[n][koff] = ld8bf(lin_w, (size_t)n * 512 + kt * 32 + koff, m);
        }
        __syncthreads();
        bf16x8 af[4];
        #pragma unroll
        for (int mt = 0; mt < 4; ++mt) af[mt] = *(const bf16x8*)&As[mt * 16 + lm][q * 8];
        #pragma unroll
        for (int nt = 0; nt < 8; ++nt) {
            bf16x8 bv = *(const bf16x8*)&Bs[wave * 128 + nt * 16 + lm][q * 8];
            #pragma unroll
            for (int mt = 0; mt < 4; ++mt)
                acc[mt][nt] = __builtin_amdgcn_mfma_f32_16x16x32_bf16(af[mt], bv, acc[mt][nt], 0, 0, 0);
        }
        __syncthreads();
    }

    float part[4][4] = {};
    #pragma unroll
    for (int nt = 0; nt < 8; ++nt) {
        const int col = wave * 128 + nt * 16 + lm;
        const float lb = ldsc(lin_b, col, m);
        const float aw = ldsc(attw, col, m);
        #pragma unroll
        for (int mt = 0; mt < 4; ++mt)
            #pragma unroll
            for (int j = 0; j < 4; ++j)
                part[mt][j] += fast_tanh(acc[mt][nt][j] + lb) * aw;
    }
    #pragma unroll
    for (int mt = 0; mt < 4; ++mt)
        #pragma unroll
        for (int j = 0; j < 4; ++j) {
            float v = part[mt][j];
            #pragma unroll
            for (int d0 = 1; d0 < 16; d0 <<= 1) v += __shfl_xor(v, d0);
            part[mt][j] = v;
        }
    if (lm == 0) {
        #pragma unroll
        for (int mt = 0; mt < 4; ++mt)
            #pragma unroll
            for (int j = 0; j < 4; ++j)
                att_part[wave][mt * 16 + q * 4 + j] = part[mt][j];
    }
    __syncthreads();
    if (tid < 64)
        att_out[(size_t)bm * 64 + tid] =
            att_part[0][tid] + att_part[1][tid] + att_part[2][tid] + att_part[3][tid];
}

// ---------------------------------------------------------------------------
// K4: masked softmax over t + weighted sum of enc rows. grid = NB.
// ---------------------------------------------------------------------------
__global__ __launch_bounds__(256) void k_softsum(
    const float* __restrict__ att, const float* __restrict__ enc,
    const int* __restrict__ lens, float* __restrict__ out,
    float* __restrict__ zero_row, int T, int NB)
{
    __shared__ float eS[64];
    __shared__ float dS;
    const int bb = blockIdx.x, tid = threadIdx.x;
    if (zero_row && bb == 0) { for (int j = tid; j < 512; j += 256) zero_row[j] = 0.f; }
    const int len = lens[bb];
    if (tid < T) {
        float a = fminf(att[(size_t)tid * NB + bb], 50.f);  // inf-guard
        eS[tid] = (tid < len) ? __expf(a) : 0.f;
    }
    __syncthreads();
    if (tid == 0) { float s = 0.f; for (int t2 = 0; t2 < T; ++t2) s += eS[t2]; dS = s + 1e-4f; }
    __syncthreads();
    const float inv = 1.f / dS;
    for (int j = tid; j < 512; j += 256) {
        float a0 = 0.f;
        for (int t2 = 0; t2 < T; ++t2) a0 += eS[t2] * enc[((size_t)t2 * NB + bb) * 512 + j];
        out[(size_t)bb * 512 + j] = fin(a0 * inv);
    }
}

// ---------------------------------------------------------------------------
// K5: sentence gather + sentence-level input projection (fp32 VALU).
// grid = 640 (one (b,t) row).
// ---------------------------------------------------------------------------
__global__ __launch_bounds__(256) void k_sent_xp(
    const int* __restrict__ sent_order, const float* __restrict__ sent_pad,
    const void* __restrict__ wih_f, const void* __restrict__ wih_b,
    const void* __restrict__ bih_f, const void* __restrict__ bih_b,
    float* __restrict__ each_sent, float* __restrict__ xp_s,
    const int* __restrict__ modep)
{
    __shared__ float aS[512];
    const int m = modep[0];
    const int r = blockIdx.x, tid = threadIdx.x;
    const int idx = sent_order[r];
    const float* src = sent_pad + (size_t)idx * 512;
    for (int j = tid; j < 512; j += 256) { float v = src[j]; aS[j] = v; each_sent[(size_t)r * 512 + j] = v; }
    __syncthreads();
    const int d = r / 40, i2 = r % 40;
    #pragma unroll
    for (int p = 0; p < 6; ++p) {
        const int o = p * 256 + tid;
        const int dirb = (o >= 768);
        const int oo = o - dirb * 768;
        const void* wsrc = dirb ? wih_b : wih_f;
        float s = ldsc(dirb ? bih_b : bih_f, oo, m);
        for (int k = 0; k < 512; k += 8) {
            float wf[8];
            ld8f(wsrc, (size_t)oo * 512 + k, m, wf);
            #pragma unroll
            for (int u = 0; u < 8; ++u) s += aS[k + u] * wf[u];
        }
        xp_s[(size_t)dirb * (40 * 16 * 768) + ((size_t)i2 * 16 + d) * 768 + oo] = s;
    }
}

// ---------------------------------------------------------------------------
// K6: cosine sims + 64->32 MLP + mask. grid = 512 ((b,m) pairs).
// ---------------------------------------------------------------------------
__global__ __launch_bounds__(256) void k_final(
    const int* __restrict__ men_sent_idx, const int* __restrict__ can_ent_idx,
    const void* __restrict__ cand_mask, const void* __restrict__ embed_ent,
    const float* __restrict__ each_sent, const float* __restrict__ doc_embs,
    const void* __restrict__ mlp_w, const void* __restrict__ mlp_b,
    void* __restrict__ out, const int* __restrict__ modep)
{
    const int bm = blockIdx.x;            // b*32 + m
    const int b = bm >> 5;
    __shared__ float sv[512], dv[512];
    __shared__ float red[256];
    __shared__ float ssA[32], dsA[32];
    __shared__ float norms[2];
    const int m = modep[0];
    const int tid = threadIdx.x;
    const int sidx = men_sent_idx[bm];
    const float* svp = each_sent + ((size_t)b * 40 + sidx) * 512;
    const float* dvp = doc_embs + (size_t)b * 512;
    float pa = 0.f, pd = 0.f;
    for (int j = tid; j < 512; j += 256) {
        float a = svp[j], d0 = dvp[j];
        sv[j] = a; dv[j] = d0; pa += a * a; pd += d0 * d0;
    }
    red[tid] = pa; __syncthreads();
    for (int s = 128; s > 0; s >>= 1) { if (tid < s) red[tid] += red[tid + s]; __syncthreads(); }
    if (tid == 0) norms[0] = sqrtf(red[0]);
    __syncthreads();
    red[tid] = pd; __syncthreads();
    for (int s = 128; s > 0; s >>= 1) { if (tid < s) red[tid] += red[tid + s]; __syncthreads(); }
    if (tid == 0) norms[1] = sqrtf(red[0]);
    __syncthreads();

    const int c = tid >> 3, jg = tid & 7;
    const int ei = can_ent_idx[(size_t)bm * 32 + c];
    float dsv = 0.f, ddv = 0.f, ne = 0.f;
    for (int k = 0; k < 64; k += 8) {
        float wf[8];
        ld8f(embed_ent, (size_t)ei * 512 + jg * 64 + k, m, wf);
        const int base = jg * 64 + k;
        #pragma unroll
        for (int u = 0; u < 8; ++u) {
            dsv += sv[base + u] * wf[u];
            ddv += dv[base + u] * wf[u];
            ne  += wf[u] * wf[u];
        }
    }
    #pragma unroll
    for (int d0 = 1; d0 < 8; d0 <<= 1) {
        dsv += __shfl_xor(dsv, d0);
        ddv += __shfl_xor(ddv, d0);
        ne  += __shfl_xor(ne, d0);
    }
    if (jg == 0) {
        const float nen = sqrtf(ne);
        const float cm = ldsc(cand_mask, (size_t)bm * 32 + c, m);
        ssA[c] = dsv / fmaxf(norms[0] * nen, 1e-8f) * cm;
        dsA[c] = ddv / fmaxf(norms[1] * nen, 1e-8f) * cm;
    }
    __syncthreads();
    if (tid < 32) {
        float o = ldsc(mlp_b, tid, m);
        for (int j2 = 0; j2 < 32; ++j2) {
            o += ssA[j2] * ldsc(mlp_w, tid * 64 + j2, m);
            o += dsA[j2] * ldsc(mlp_w, tid * 64 + 32 + j2, m);
        }
        const float maskv = (ssA[tid] != 0.f) ? 1.f : 0.f;
        const float v = fin(o * maskv);
        if (m) ((unsigned short*)out)[(size_t)bm * 32 + tid] = f2bfraw(v);
        else   ((float*)out)[(size_t)bm * 32 + tid] = v;
    }
}

// ---------------------------------------------------------------------------
extern "C" void kernel_launch(void* const* d_in, const int* in_sizes, int n_in,
                              void* d_out, int out_size, void* d_ws, size_t ws_size,
                              hipStream_t stream)
{
    (void)in_sizes; (void)n_in; (void)out_size;
    const int* batch_doc    = (const int*)d_in[0];
    const int* sent_order   = (const int*)d_in[1];
    const int* length_sent  = (const int*)d_in[2];
    const int* length_doc   = (const int*)d_in[3];
    const int* men_sent_idx = (const int*)d_in[4];
    const int* can_ent_idx  = (const int*)d_in[5];
    const void* cand_mask = d_in[6];
    const void* embed_doc = d_in[7];
    const void* embed_ent = d_in[8];
    const void* wWihF = d_in[9];
    const void* wWhhF = d_in[10];
    const void* wBihF = d_in[11];
    const void* wBhhF = d_in[12];
    const void* wWihB = d_in[13];
    const void* wWhhB = d_in[14];
    const void* wBihB = d_in[15];
    const void* wBhhB = d_in[16];
    const void* wLinW = d_in[17];
    const void* wLinB = d_in[18];
    const void* wAttw = d_in[19];
    const void* sWihF = d_in[20];
    const void* sWhhF = d_in[21];
    const void* sBihF = d_in[22];
    const void* sBhhF = d_in[23];
    const void* sWihB = d_in[24];
    const void* sWhhB = d_in[25];
    const void* sBihB = d_in[26];
    const void* sBhhB = d_in[27];
    const void* sLinW = d_in[28];
    const void* sLinB = d_in[29];
    const void* sAttw = d_in[30];
    const void* mlpW  = d_in[31];
    const void* mlpB  = d_in[32];

    // ---- choose word-level phase size nb so the footprint fits ws_size ----
    auto need = [](int nb) -> size_t {
        size_t xpc  = (size_t)2 * 64 * nb * 768 * 2;   // fp16 xp chunk
        size_t encc = (size_t)64 * nb * 512 * 4;       // fp32 enc chunk
        size_t attc = (size_t)64 * nb * 4;
        size_t fixed = ((size_t)328192 + 327680 + 983040 + 327680 + 640 + 8192) * 4;
        return xpc + encc + attc + fixed + (1u << 20);
    };
    int nb = 320;                                      // 320,160,80,40,16
    while (need(nb) > ws_size && nb > 16) nb = (nb == 40) ? 16 : (nb >> 1);

    char* base = (char*)d_ws;
    size_t off = 0;
    auto take = [&](size_t bytes) -> void* {
        void* p = base + off; off += (bytes + 255) & ~(size_t)255; return p;
    };
    int*   mode      = (int*)take(256);
    unsigned short* xp_c = (unsigned short*)take((size_t)2 * 64 * nb * 768 * 2);
    float* enc_c     = (float*)take((size_t)64 * nb * 512 * 4);
    float* att_c     = (float*)take((size_t)64 * nb * 4);
    float* sent_pad  = (float*)take((size_t)328192 * 4);   // [641][512], row0 zeros
    float* each_sent = (float*)take((size_t)327680 * 4);   // [16][40][512]
    float* xp_s      = (float*)take((size_t)983040 * 4);   // [2][40][16][768]
    float* enc_s     = (float*)take((size_t)327680 * 4);   // [40][16][512]
    float* att_s     = (float*)take((size_t)640 * 4);      // [40][16]
    float* doc_embs  = (float*)take((size_t)8192 * 4);     // [16][512]

    // ---- dtype probe ----
    k_probe<<<1, 64, 0, stream>>>((const unsigned short*)wWhhF, mode);

    // ---- word level, phased over sentence chunks ----
    for (int b0 = 0; b0 < 640; b0 += nb) {
        k_xp_word<<<dim3(nb, 6), 256, 0, stream>>>(embed_doc, batch_doc, wWihF, wWihB,
                                                   wBihF, wBihB, xp_c, b0, nb, mode);
        k_gru<<<2 * (nb / 16), 256, 0, stream>>>(xp_c, 1, wWhhF, wWhhB, wBhhF, wBhhB,
                                                 length_sent + b0, enc_c, 64, nb, mode);
        k_att<<<nb, 256, 0, stream>>>(enc_c, wLinW, wLinB, wAttw, att_c, mode);
        k_softsum<<<nb, 256, 0, stream>>>(att_c, enc_c, length_sent + b0,
                                          sent_pad + (size_t)(1 + b0) * 512,
                                          (b0 == 0) ? sent_pad : nullptr, 64, nb);
    }
    // ---- sentence level ----
    k_sent_xp<<<640, 256, 0, stream>>>(sent_order, sent_pad, sWihF, sWihB, sBihF, sBihB,
                                       each_sent, xp_s, mode);
    k_gru<<<2, 256, 0, stream>>>(xp_s, 0, sWhhF, sWhhB, sBhhF, sBhhB,
                                 length_doc, enc_s, 40, 16, mode);
    k_att<<<10, 256, 0, stream>>>(enc_s, sLinW, sLinB, sAttw, att_s, mode);
    k_softsum<<<16, 256, 0, stream>>>(att_s, enc_s, length_doc, doc_embs, nullptr, 40, 16);
    // ---- scoring ----
    k_final<<<512, 256, 0, stream>>>(men_sent_idx, can_ent_idx, cand_mask, embed_ent,
                                     each_sent, doc_embs, mlpW, mlpB, d_out, mode);
}

// Round 4
// 2309.709 us; speedup vs baseline: 2.5962x; 2.5962x over previous
//
#include <hip/hip_runtime.h>
#include <cstdint>
#include <cstddef>

// ---------------------------------------------------------------------------
// HAN forward on gfx950. Float input dtype (fp32 vs bf16) unknown at build
// time -> probe kernel writes mode flag; prep kernels convert all hot-path
// operands to bf16 once (weights swizzled into MFMA-fragment order), so the
// hot kernels are single-mode. GRU h uses hi+lo bf16 split (passed at 9.8e-4).
// ---------------------------------------------------------------------------

typedef __attribute__((ext_vector_type(8))) short bf16x8;   // 8 bf16 = 4 VGPR
typedef __attribute__((ext_vector_type(4))) float f32x4;

__device__ __forceinline__ float bfraw2f(unsigned int u16) {
    unsigned int x = u16 << 16; float f; __builtin_memcpy(&f, &x, 4); return f;
}
__device__ __forceinline__ unsigned short f2bfraw(float f) {  // RNE
    unsigned int u; __builtin_memcpy(&u, &f, 4);
    unsigned int r = u + 0x7fffu + ((u >> 16) & 1u);
    return (unsigned short)(r >> 16);
}
__device__ __forceinline__ unsigned short f2h(float f) {
    _Float16 h = (_Float16)f; unsigned short u; __builtin_memcpy(&u, &h, 2); return u;
}
__device__ __forceinline__ float h2f(unsigned short u) {
    _Float16 h; __builtin_memcpy(&h, &u, 2); return (float)h;
}
__device__ __forceinline__ float bflo(unsigned int p) {
    unsigned int x = p << 16; float f; __builtin_memcpy(&f, &x, 4); return f;
}
__device__ __forceinline__ float bfhi(unsigned int p) {
    unsigned int x = p & 0xffff0000u; float f; __builtin_memcpy(&f, &x, 4); return f;
}
__device__ __forceinline__ float fast_sigmoid(float x) { return 1.f / (1.f + __expf(-x)); }
__device__ __forceinline__ float fast_tanh(float x) {
    x = fminf(fmaxf(x, -30.f), 30.f);
    float e = __expf(2.f * x);
    return (e - 1.f) / (e + 1.f);
}
__device__ __forceinline__ float fin(float x) {
    return (x == x && fabsf(x) < 1e30f) ? x : 0.f;
}

// ---- dual-mode input adapters (m=1: bf16 u16 buffer, m=0: fp32 buffer) ----
__device__ __forceinline__ float ldsc(const void* p, size_t i, int m) {
    return m ? bfraw2f(((const unsigned short*)p)[i]) : ((const float*)p)[i];
}
__device__ __forceinline__ bf16x8 ld8bf(const void* p, size_t ei, int m) {
    if (m) return *(const bf16x8*)((const unsigned short*)p + ei);
    const float* f = (const float*)p + ei;
    f32x4 a = *(const f32x4*)f, b = *(const f32x4*)(f + 4);
    bf16x8 r;
    r[0] = (short)f2bfraw(a[0]); r[1] = (short)f2bfraw(a[1]);
    r[2] = (short)f2bfraw(a[2]); r[3] = (short)f2bfraw(a[3]);
    r[4] = (short)f2bfraw(b[0]); r[5] = (short)f2bfraw(b[1]);
    r[6] = (short)f2bfraw(b[2]); r[7] = (short)f2bfraw(b[3]);
    return r;
}
__device__ __forceinline__ void ld8f(const void* p, size_t ei, int m, float* o) {
    if (m) {
        uint4 wv = *(const uint4*)((const unsigned short*)p + ei);
        o[0] = bflo(wv.x); o[1] = bfhi(wv.x); o[2] = bflo(wv.y); o[3] = bfhi(wv.y);
        o[4] = bflo(wv.z); o[5] = bfhi(wv.z); o[6] = bflo(wv.w); o[7] = bfhi(wv.w);
    } else {
        const float* f = (const float*)p + ei;
        #pragma unroll
        for (int i = 0; i < 8; ++i) o[i] = f[i];
    }
}

// ---------------------------------------------------------------------------
// K0: dtype probe. flag[0] = mode (1=bf16, 0=fp32); flag[1] = 1 always
// (pointer alias used to force-bf16 consumers of converted buffers).
// ---------------------------------------------------------------------------
__global__ void k_probe(const unsigned short* __restrict__ w, int* __restrict__ flag) {
    if (threadIdx.x == 0) {
        int bad = 0;
        for (int i = 0; i < 512; ++i) {
            float v = bfraw2f(w[i]);
            if (!(fabsf(v) <= 1.0f)) bad++;   // NaN lands here too
        }
        flag[0] = (bad == 0) ? 1 : 0;
        flag[1] = 1;
    }
}

// ---------------------------------------------------------------------------
// P1: generic dual-mode -> bf16 convert (identity copy in bf16 mode).
// ---------------------------------------------------------------------------
__global__ void p_cvt(const void* __restrict__ src, unsigned short* __restrict__ dst,
                      int n, const int* __restrict__ modep) {
    const int m = modep[0];
    for (int i = blockIdx.x * 256 + threadIdx.x; i < n; i += gridDim.x * 256)
        dst[i] = f2bfraw(ldsc(src, i, m));
}

// ---------------------------------------------------------------------------
// P2: Whh (768x256) -> bf16, MFMA-fragment-ordered:
// frag f = (wave*12 + g)*8 + ks, g=reg*4+nt; elem addr = f*512 + lane*8 + e.
// Source elem = whh[(reg*256 + wave*64 + nt*16 + lm)*256 + ks*32 + q*8 + e].
// One dwordx4 per lane per fragment load in k_gru, fully coalesced.
// ---------------------------------------------------------------------------
__global__ void p_whh_swz(const void* __restrict__ whh, unsigned short* __restrict__ dst,
                          const int* __restrict__ modep) {
    const int m = modep[0];
    const int idx = blockIdx.x * 256 + threadIdx.x;    // 24576 = 4*12*8*64
    if (idx >= 24576) return;
    const int lane = idx & 63, ks = (idx >> 6) & 7;
    const int g = (idx >> 9) % 12, wave = idx / (512 * 12);
    const int lm = lane & 15, q = lane >> 4;
    const int reg = g >> 2, nt = g & 3;
    const int row = reg * 256 + wave * 64 + nt * 16 + lm;
    const size_t src = (size_t)row * 256 + ks * 32 + q * 8;
    const size_t d = (size_t)idx * 8;
    #pragma unroll
    for (int e = 0; e < 8; ++e) dst[d + e] = f2bfraw(ldsc(whh, src + e, m));
}

// ---------------------------------------------------------------------------
// K1: gathered word projection. xp[dir][t][bl][768] fp16.
// A = embed rows (bf16 via amode), B = wih bf16 [1536][512]. grid (nb, 6).
// ---------------------------------------------------------------------------
__global__ __launch_bounds__(256, 2) void k_xp_word(
    const void* __restrict__ embA, const int* __restrict__ batch_doc,
    const unsigned short* __restrict__ wih,       // bf16 [1536][512]
    const void* __restrict__ bih_f, const void* __restrict__ bih_b,
    unsigned short* __restrict__ xp, int b0, int nb,
    const int* __restrict__ amode, const int* __restrict__ modep)
{
    __shared__ unsigned short As[64][40];
    __shared__ unsigned short Bs[256][40];
    const int am = amode[0], m = modep[0];
    const int bm = blockIdx.x, bc = blockIdx.y;
    const int tid = threadIdx.x;
    const int wave = tid >> 6, lane = tid & 63, lm = lane & 15, q = lane >> 4;
    const int arow = tid >> 2, akoff = (tid & 3) * 8;
    const int r = bm * 64 + arow;           // phase-local row = t*nb + bl
    const int tt = r / nb, bl = r - tt * nb;
    const size_t aei = (size_t)batch_doc[(b0 + bl) * 64 + tt] * 512 + akoff;

    const f32x4 fzero = {0.f, 0.f, 0.f, 0.f};
    f32x4 acc[4][4];
    #pragma unroll
    for (int i = 0; i < 4; ++i)
        #pragma unroll
        for (int j = 0; j < 4; ++j) acc[i][j] = fzero;

    for (int kt = 0; kt < 16; ++kt) {
        *(bf16x8*)&As[arow][akoff] = ld8bf(embA, aei + kt * 32, am);
        #pragma unroll
        for (int ld = 0; ld < 4; ++ld) {
            int e = ld * 256 + tid;
            int n = e >> 2, koff = (e & 3) * 8;
            int gn = bc * 256 + n;
            *(uint4*)&Bs[n][koff] = *(const uint4*)(wih + (size_t)gn * 512 + kt * 32 + koff);
        }
        __syncthreads();
        bf16x8 af[4], bv[4];
        #pragma unroll
        for (int mt = 0; mt < 4; ++mt) af[mt] = *(const bf16x8*)&As[mt * 16 + lm][q * 8];
        #pragma unroll
        for (int nt = 0; nt < 4; ++nt) bv[nt] = *(const bf16x8*)&Bs[wave * 64 + nt * 16 + lm][q * 8];
        #pragma unroll
        for (int mt = 0; mt < 4; ++mt)
            #pragma unroll
            for (int nt = 0; nt < 4; ++nt)
                acc[mt][nt] = __builtin_amdgcn_mfma_f32_16x16x32_bf16(af[mt], bv[nt], acc[mt][nt], 0, 0, 0);
        __syncthreads();
    }

    const size_t XPT = (size_t)64 * nb * 768;
    #pragma unroll
    for (int nt = 0; nt < 4; ++nt) {
        const int cn = bc * 256 + wave * 64 + nt * 16 + lm;
        const int dirb = (cn >= 768);
        const int o = cn - dirb * 768;
        const float bias = ldsc(dirb ? bih_b : bih_f, o, m);
        #pragma unroll
        for (int mt = 0; mt < 4; ++mt)
            #pragma unroll
            for (int j = 0; j < 4; ++j) {
                const int rr = bm * 64 + mt * 16 + q * 4 + j;
                xp[(dirb ? XPT : 0) + (size_t)rr * 768 + o] = f2h(acc[mt][nt][j] + bias);
            }
    }
}

// ---------------------------------------------------------------------------
// K2: pipelined GRU recurrence. One block per (dir, 16-row group), 4 waves.
// B (Whh) streamed from swizzled bf16 (L2-resident) with 2-stage register
// pipeline; xp staged per step into LDS with register prefetch of t+1;
// h in LDS fp32 + hi/lo bf16 mirrors. grid = 2*(NB/16). xp is fp16.
// ---------------------------------------------------------------------------
__global__ __launch_bounds__(256, 1) void k_gru(
    const unsigned short* __restrict__ xp,          // fp16 [dir][T*NB][768]
    const unsigned short* __restrict__ wswz_f,      // bf16 swizzled 393216
    const unsigned short* __restrict__ wswz_b,
    const void* __restrict__ bhh_f, const void* __restrict__ bhh_b,
    const int* __restrict__ lens, float* __restrict__ enc, int T, int NB,
    const int* __restrict__ modep)
{
    __shared__ float hS[16][260];
    __shared__ unsigned short hHi[16][264];
    __shared__ unsigned short hLo[16][264];
    __shared__ unsigned short xpS[16][776];   // fp16, pitch 1552B (16B-mult)
    __shared__ float bhhS[768];
    __shared__ int lensS[16];
    const int m = modep[0];
    const int tid = threadIdx.x;
    const int wave = tid >> 6, lane = tid & 63, lm = lane & 15, q = lane >> 4;
    const int dir = blockIdx.x & 1, sg = blockIdx.x >> 1;
    const int s0 = sg << 4;
    const unsigned short* wsw =
        (dir ? wswz_b : wswz_f) + (size_t)wave * 12 * 8 * 512 + (size_t)lane * 8;
    const void* bhh = dir ? bhh_b : bhh_f;
    const unsigned short* xpd = xp + (dir ? (size_t)T * NB * 768 : 0);

    for (int e = tid; e < 16 * 260; e += 256) (&hS[0][0])[e] = 0.f;
    for (int e = tid; e < 16 * 264; e += 256) { (&hHi[0][0])[e] = 0; (&hLo[0][0])[e] = 0; }
    for (int j = tid; j < 768; j += 256) bhhS[j] = ldsc(bhh, j, m);
    if (tid < 16) lensS[tid] = lens[s0 + tid];

    // prologue: stage xp(t0) into xpS
    {
        const int t0 = dir ? (T - 1) : 0;
        const unsigned short* xrow = xpd + ((size_t)t0 * NB + s0) * 768;
        #pragma unroll
        for (int i = 0; i < 6; ++i) {
            int e = tid + i * 256;                 // [0,1536) dwordx4 slots
            uint4 v = *(const uint4*)(xrow + e * 8);
            *(uint4*)&xpS[e / 96][(e % 96) * 8] = v;
        }
    }
    __syncthreads();

    const f32x4 fzero = {0.f, 0.f, 0.f, 0.f};
    uint4 stg[6];
    for (int step = 0; step < T; ++step) {
        const int t = dir ? (T - 1 - step) : step;
        // A fragments from h mirrors
        bf16x8 ahi[8], alo[8];
        #pragma unroll
        for (int ks = 0; ks < 8; ++ks) {
            ahi[ks] = *(const bf16x8*)&hHi[lm][ks * 32 + q * 8];
            alo[ks] = *(const bf16x8*)&hLo[lm][ks * 32 + q * 8];
        }
        __syncthreads();   // all h + xpS reads of previous phase complete

        // prefetch next step's xp tile into registers (overlaps MFMA)
        const bool havenext = (step + 1 < T);
        if (havenext) {
            const int tn = dir ? (T - 2 - step) : (step + 1);
            const unsigned short* xrow = xpd + ((size_t)tn * NB + s0) * 768;
            #pragma unroll
            for (int i = 0; i < 6; ++i)
                stg[i] = *(const uint4*)(xrow + (tid + i * 256) * 8);
        }

        // MFMA with 2-stage B pipeline (B constant over steps, L2-resident)
        f32x4 acc[12];
        #pragma unroll
        for (int i = 0; i < 12; ++i) acc[i] = fzero;
        bf16x8 bcur[8], bnxt[8];
        #pragma unroll
        for (int ks = 0; ks < 8; ++ks) bcur[ks] = *(const bf16x8*)(wsw + ks * 512);
        #pragma unroll
        for (int g = 0; g < 12; ++g) {
            if (g < 11) {
                #pragma unroll
                for (int ks = 0; ks < 8; ++ks)
                    bnxt[ks] = *(const bf16x8*)(wsw + ((g + 1) * 8 + ks) * 512);
            }
            #pragma unroll
            for (int ks = 0; ks < 8; ++ks) {
                acc[g] = __builtin_amdgcn_mfma_f32_16x16x32_bf16(ahi[ks], bcur[ks], acc[g], 0, 0, 0);
                acc[g] = __builtin_amdgcn_mfma_f32_16x16x32_bf16(alo[ks], bcur[ks], acc[g], 0, 0, 0);
            }
            #pragma unroll
            for (int ks = 0; ks < 8; ++ks) bcur[ks] = bnxt[ks];
        }

        // gates: lane element (s=q*4+j, col=wave*64+nt*16+lm) == acc slots
        #pragma unroll
        for (int nt = 0; nt < 4; ++nt) {
            const int col = wave * 64 + nt * 16 + lm;
            const float br = bhhS[col], bz = bhhS[256 + col], bn = bhhS[512 + col];
            #pragma unroll
            for (int j = 0; j < 4; ++j) {
                const int s = q * 4 + j;
                const float xr = h2f(xpS[s][col]);
                const float xz = h2f(xpS[s][256 + col]);
                const float xn = h2f(xpS[s][512 + col]);
                const float rr = fast_sigmoid(xr + acc[nt][j] + br);
                const float zz = fast_sigmoid(xz + acc[4 + nt][j] + bz);
                const float nn = fast_tanh(xn + rr * (acc[8 + nt][j] + bn));
                const float hold = hS[s][col];
                float hnew = (1.f - zz) * nn + zz * hold;
                const bool v = (t < lensS[s]);
                hnew = v ? hnew : hold;
                hS[s][col] = hnew;
                const unsigned short uh = f2bfraw(hnew);
                hHi[s][col] = uh;
                hLo[s][col] = f2bfraw(hnew - bfraw2f(uh));
                enc[((size_t)t * NB + s0 + s) * 512 + (size_t)dir * 256 + col] = v ? hnew : 0.f;
            }
        }
        __syncthreads();   // gates' xpS reads + h writes drained

        if (havenext) {    // write prefetched xp tile (read next iteration)
            #pragma unroll
            for (int i = 0; i < 6; ++i) {
                int e = tid + i * 256;
                *(uint4*)&xpS[e / 96][(e % 96) * 8] = stg[i];
            }
        }
    }
}

// ---------------------------------------------------------------------------
// K3: attention scores, GEMM (M x 512)@(512x512) + fused tanh*attw reduce.
// ---------------------------------------------------------------------------
__global__ __launch_bounds__(256, 1) void k_att(
    const float* __restrict__ enc, const unsigned short* __restrict__ lin_w, // bf16
    const void* __restrict__ lin_b, const void* __restrict__ attw,
    float* __restrict__ att_out, const int* __restrict__ modep)
{
    __shared__ unsigned short As[64][40];
    __shared__ unsigned short Bs[512][40];
    __shared__ float att_part[4][64];
    const int m = modep[0];
    const int bm = blockIdx.x;
    const int tid = threadIdx.x;
    const int wave = tid >> 6, lane = tid & 63, lm = lane & 15, q = lane >> 4;
    const int arow = tid >> 2, akoff = (tid & 3) * 8;
    const float* aptr = enc + (size_t)(bm * 64 + arow) * 512 + akoff;

    const f32x4 fzero = {0.f, 0.f, 0.f, 0.f};
    f32x4 acc[4][8];
    #pragma unroll
    for (int i = 0; i < 4; ++i)
        #pragma unroll
        for (int j = 0; j < 8; ++j) acc[i][j] = fzero;

    for (int kt = 0; kt < 16; ++kt) {
        f32x4 f0 = *(const f32x4*)(aptr + kt * 32);
        f32x4 f1 = *(const f32x4*)(aptr + kt * 32 + 4);
        bf16x8 cv;
        cv[0] = (short)f2bfraw(f0[0]); cv[1] = (short)f2bfraw(f0[1]);
        cv[2] = (short)f2bfraw(f0[2]); cv[3] = (short)f2bfraw(f0[3]);
        cv[4] = (short)f2bfraw(f1[0]); cv[5] = (short)f2bfraw(f1[1]);
        cv[6] = (short)f2bfraw(f1[2]); cv[7] = (short)f2bfraw(f1[3]);
        *(bf16x8*)&As[arow][akoff] = cv;
        #pragma unroll
        for (int ld = 0; ld < 8; ++ld) {
            int e = ld * 256 + tid;
            int n = e >> 2, koff = (e & 3) * 8;
            *(uint4*)&Bs[n][koff] = *(const uint4*)(lin_w + (size_t)n * 512 + kt * 32 + koff);
        }
        __syncthreads();
        bf16x8 af[4];
        #pragma unroll
        for (int mt = 0; mt < 4; ++mt) af[mt] = *(const bf16x8*)&As[mt * 16 + lm][q * 8];
        #pragma unroll
        for (int nt = 0; nt < 8; ++nt) {
            bf16x8 bv = *(const bf16x8*)&Bs[wave * 128 + nt * 16 + lm][q * 8];
            #pragma unroll
            for (int mt = 0; mt < 4; ++mt)
                acc[mt][nt] = __builtin_amdgcn_mfma_f32_16x16x32_bf16(af[mt], bv, acc[mt][nt], 0, 0, 0);
        }
        __syncthreads();
    }

    float part[4][4] = {};
    #pragma unroll
    for (int nt = 0; nt < 8; ++nt) {
        const int col = wave * 128 + nt * 16 + lm;
        const float lb = ldsc(lin_b, col, m);
        const float aw = ldsc(attw, col, m);
        #pragma unroll
        for (int mt = 0; mt < 4; ++mt)
            #pragma unroll
            for (int j = 0; j < 4; ++j)
                part[mt][j] += fast_tanh(acc[mt][nt][j] + lb) * aw;
    }
    #pragma unroll
    for (int mt = 0; mt < 4; ++mt)
        #pragma unroll
        for (int j = 0; j < 4; ++j) {
            float v = part[mt][j];
            #pragma unroll
            for (int d0 = 1; d0 < 16; d0 <<= 1) v += __shfl_xor(v, d0);
            part[mt][j] = v;
        }
    if (lm == 0) {
        #pragma unroll
        for (int mt = 0; mt < 4; ++mt)
            #pragma unroll
            for (int j = 0; j < 4; ++j)
                att_part[wave][mt * 16 + q * 4 + j] = part[mt][j];
    }
    __syncthreads();
    if (tid < 64)
        att_out[(size_t)bm * 64 + tid] =
            att_part[0][tid] + att_part[1][tid] + att_part[2][tid] + att_part[3][tid];
}

// ---------------------------------------------------------------------------
// K4: masked softmax over t + weighted sum of enc rows. grid = NB.
// ---------------------------------------------------------------------------
__global__ __launch_bounds__(256) void k_softsum(
    const float* __restrict__ att, const float* __restrict__ enc,
    const int* __restrict__ lens, float* __restrict__ out,
    float* __restrict__ zero_row, int T, int NB)
{
    __shared__ float eS[64];
    __shared__ float dS;
    const int bb = blockIdx.x, tid = threadIdx.x;
    if (zero_row && bb == 0) { for (int j = tid; j < 512; j += 256) zero_row[j] = 0.f; }
    const int len = lens[bb];
    if (tid < T) {
        float a = fminf(att[(size_t)tid * NB + bb], 50.f);
        eS[tid] = (tid < len) ? __expf(a) : 0.f;
    }
    __syncthreads();
    if (tid == 0) { float s = 0.f; for (int t2 = 0; t2 < T; ++t2) s += eS[t2]; dS = s + 1e-4f; }
    __syncthreads();
    const float inv = 1.f / dS;
    for (int j = tid; j < 512; j += 256) {
        float a0 = 0.f;
        for (int t2 = 0; t2 < T; ++t2) a0 += eS[t2] * enc[((size_t)t2 * NB + bb) * 512 + j];
        out[(size_t)bb * 512 + j] = fin(a0 * inv);
    }
}

// ---------------------------------------------------------------------------
// K5: sentence gather + sentence input projection; writes xp_s fp16.
// grid = 640 (one (d,t) row).
// ---------------------------------------------------------------------------
__global__ __launch_bounds__(256) void k_sent_xp(
    const int* __restrict__ sent_order, const float* __restrict__ sent_pad,
    const unsigned short* __restrict__ swih,      // bf16 [1536][512]
    const void* __restrict__ bih_f, const void* __restrict__ bih_b,
    float* __restrict__ each_sent, unsigned short* __restrict__ xp_s,
    const int* __restrict__ modep)
{
    __shared__ float aS[512];
    const int m = modep[0];
    const int r = blockIdx.x, tid = threadIdx.x;
    const int idx = sent_order[r];
    const float* src = sent_pad + (size_t)idx * 512;
    for (int j = tid; j < 512; j += 256) { float v = src[j]; aS[j] = v; each_sent[(size_t)r * 512 + j] = v; }
    __syncthreads();
    const int d = r / 40, i2 = r % 40;
    #pragma unroll
    for (int p = 0; p < 6; ++p) {
        const int o = p * 256 + tid;
        const int dirb = (o >= 768);
        const int oo = o - dirb * 768;
        float s = ldsc(dirb ? bih_b : bih_f, oo, m);
        const unsigned short* wrow = swih + (size_t)o * 512;
        for (int k = 0; k < 512; k += 8) {
            const uint4 wv = *(const uint4*)(wrow + k);
            float wf[8];
            wf[0] = bflo(wv.x); wf[1] = bfhi(wv.x); wf[2] = bflo(wv.y); wf[3] = bfhi(wv.y);
            wf[4] = bflo(wv.z); wf[5] = bfhi(wv.z); wf[6] = bflo(wv.w); wf[7] = bfhi(wv.w);
            #pragma unroll
            for (int u = 0; u < 8; ++u) s += aS[k + u] * wf[u];
        }
        xp_s[(size_t)dirb * (40 * 16 * 768) + ((size_t)i2 * 16 + d) * 768 + oo] = f2h(s);
    }
}

// ---------------------------------------------------------------------------
// K6: cosine sims + 64->32 MLP + mask. grid = 512 ((b,m) pairs).
// ---------------------------------------------------------------------------
__global__ __launch_bounds__(256) void k_final(
    const int* __restrict__ men_sent_idx, const int* __restrict__ can_ent_idx,
    const void* __restrict__ cand_mask, const void* __restrict__ embed_ent,
    const float* __restrict__ each_sent, const float* __restrict__ doc_embs,
    const void* __restrict__ mlp_w, const void* __restrict__ mlp_b,
    void* __restrict__ out, const int* __restrict__ modep)
{
    const int bm = blockIdx.x;
    const int b = bm >> 5;
    __shared__ float sv[512], dv[512];
    __shared__ float red[256];
    __shared__ float ssA[32], dsA[32];
    __shared__ float norms[2];
    const int m = modep[0];
    const int tid = threadIdx.x;
    const int sidx = men_sent_idx[bm];
    const float* svp = each_sent + ((size_t)b * 40 + sidx) * 512;
    const float* dvp = doc_embs + (size_t)b * 512;
    float pa = 0.f, pd = 0.f;
    for (int j = tid; j < 512; j += 256) {
        float a = svp[j], d0 = dvp[j];
        sv[j] = a; dv[j] = d0; pa += a * a; pd += d0 * d0;
    }
    red[tid] = pa; __syncthreads();
    for (int s = 128; s > 0; s >>= 1) { if (tid < s) red[tid] += red[tid + s]; __syncthreads(); }
    if (tid == 0) norms[0] = sqrtf(red[0]);
    __syncthreads();
    red[tid] = pd; __syncthreads();
    for (int s = 128; s > 0; s >>= 1) { if (tid < s) red[tid] += red[tid + s]; __syncthreads(); }
    if (tid == 0) norms[1] = sqrtf(red[0]);
    __syncthreads();

    const int c = tid >> 3, jg = tid & 7;
    const int ei = can_ent_idx[(size_t)bm * 32 + c];
    float dsv = 0.f, ddv = 0.f, ne = 0.f;
    for (int k = 0; k < 64; k += 8) {
        float wf[8];
        ld8f(embed_ent, (size_t)ei * 512 + jg * 64 + k, m, wf);
        const int base = jg * 64 + k;
        #pragma unroll
        for (int u = 0; u < 8; ++u) {
            dsv += sv[base + u] * wf[u];
            ddv += dv[base + u] * wf[u];
            ne  += wf[u] * wf[u];
        }
    }
    #pragma unroll
    for (int d0 = 1; d0 < 8; d0 <<= 1) {
        dsv += __shfl_xor(dsv, d0);
        ddv += __shfl_xor(ddv, d0);
        ne  += __shfl_xor(ne, d0);
    }
    if (jg == 0) {
        const float nen = sqrtf(ne);
        const float cm = ldsc(cand_mask, (size_t)bm * 32 + c, m);
        ssA[c] = dsv / fmaxf(norms[0] * nen, 1e-8f) * cm;
        dsA[c] = ddv / fmaxf(norms[1] * nen, 1e-8f) * cm;
    }
    __syncthreads();
    if (tid < 32) {
        float o = ldsc(mlp_b, tid, m);
        for (int j2 = 0; j2 < 32; ++j2) {
            o += ssA[j2] * ldsc(mlp_w, tid * 64 + j2, m);
            o += dsA[j2] * ldsc(mlp_w, tid * 64 + 32 + j2, m);
        }
        const float maskv = (ssA[tid] != 0.f) ? 1.f : 0.f;
        const float v = fin(o * maskv);
        if (m) ((unsigned short*)out)[(size_t)bm * 32 + tid] = f2bfraw(v);
        else   ((float*)out)[(size_t)bm * 32 + tid] = v;
    }
}

// ---------------------------------------------------------------------------
extern "C" void kernel_launch(void* const* d_in, const int* in_sizes, int n_in,
                              void* d_out, int out_size, void* d_ws, size_t ws_size,
                              hipStream_t stream)
{
    (void)in_sizes; (void)n_in; (void)out_size;
    const int* batch_doc    = (const int*)d_in[0];
    const int* sent_order   = (const int*)d_in[1];
    const int* length_sent  = (const int*)d_in[2];
    const int* length_doc   = (const int*)d_in[3];
    const int* men_sent_idx = (const int*)d_in[4];
    const int* can_ent_idx  = (const int*)d_in[5];
    const void* cand_mask = d_in[6];
    const void* embed_doc = d_in[7];
    const void* embed_ent = d_in[8];
    const void* wWihF = d_in[9];
    const void* wWhhF = d_in[10];
    const void* wBihF = d_in[11];
    const void* wBhhF = d_in[12];
    const void* wWihB = d_in[13];
    const void* wWhhB = d_in[14];
    const void* wBihB = d_in[15];
    const void* wBhhB = d_in[16];
    const void* wLinW = d_in[17];
    const void* wLinB = d_in[18];
    const void* wAttw = d_in[19];
    const void* sWihF = d_in[20];
    const void* sWhhF = d_in[21];
    const void* sBihF = d_in[22];
    const void* sBhhF = d_in[23];
    const void* sWihB = d_in[24];
    const void* sWhhB = d_in[25];
    const void* sBihB = d_in[26];
    const void* sBhhB = d_in[27];
    const void* sLinW = d_in[28];
    const void* sLinB = d_in[29];
    const void* sAttw = d_in[30];
    const void* mlpW  = d_in[31];
    const void* mlpB  = d_in[32];

    // sizes
    const size_t N_EMB   = (size_t)50000 * 512;
    const size_t FIXED_CORE =
        256 +                                   // mode
        4 * (size_t)393216 * 2 +                // 4 swizzled Whh
        (size_t)1536 * 512 * 2 +                // word wih bf16
        (size_t)512 * 512 * 2 +                 // word lin bf16
        (size_t)1536 * 512 * 2 +                // sent wih bf16
        (size_t)512 * 512 * 2 +                 // sent lin bf16
        (size_t)328192 * 4 +                    // sent_pad
        (size_t)327680 * 4 +                    // each_sent
        (size_t)983040 * 2 +                    // xp_s fp16
        (size_t)327680 * 4 +                    // enc_s
        (size_t)640 * 4 +                       // att_s
        (size_t)8192 * 4 + 65536;               // doc_embs + align slack
    auto need = [&](int nb, int emb) -> size_t {
        return FIXED_CORE + (size_t)nb * (196608 + 131072 + 256)
             + (emb ? N_EMB * 2 : 0) + (1u << 20);
    };
    int emb_cvt = 1, nb = 320;
    {
        const int ladder[5] = {320, 160, 80, 40, 16};
        bool found = false;
        for (int e = 1; e >= 0 && !found; --e)
            for (int i = 0; i < 5 && !found; ++i)
                if (need(ladder[i], e) <= ws_size) { emb_cvt = e; nb = ladder[i]; found = true; }
    }

    char* base = (char*)d_ws;
    size_t off = 0;
    auto take = [&](size_t bytes) -> void* {
        void* p = base + off; off += (bytes + 255) & ~(size_t)255; return p;
    };
    int* mode = (int*)take(256);
    unsigned short* swzWF = (unsigned short*)take((size_t)393216 * 2);
    unsigned short* swzWB = (unsigned short*)take((size_t)393216 * 2);
    unsigned short* swzSF = (unsigned short*)take((size_t)393216 * 2);
    unsigned short* swzSB = (unsigned short*)take((size_t)393216 * 2);
    unsigned short* wih_w = (unsigned short*)take((size_t)1536 * 512 * 2);
    unsigned short* lin_w = (unsigned short*)take((size_t)512 * 512 * 2);
    unsigned short* swih  = (unsigned short*)take((size_t)1536 * 512 * 2);
    unsigned short* slin  = (unsigned short*)take((size_t)512 * 512 * 2);
    float* sent_pad  = (float*)take((size_t)328192 * 4);
    float* each_sent = (float*)take((size_t)327680 * 4);
    unsigned short* xp_s = (unsigned short*)take((size_t)983040 * 2);
    float* enc_s     = (float*)take((size_t)327680 * 4);
    float* att_s     = (float*)take((size_t)640 * 4);
    float* doc_embs  = (float*)take((size_t)8192 * 4);
    unsigned short* xp_c = (unsigned short*)take((size_t)nb * 196608);
    float* enc_c     = (float*)take((size_t)nb * 131072);
    float* att_c     = (float*)take((size_t)nb * 256);
    unsigned short* emb_bf = emb_cvt ? (unsigned short*)take(N_EMB * 2) : nullptr;

    // ---- probe + prep ----
    k_probe<<<1, 64, 0, stream>>>((const unsigned short*)wWhhF, mode);
    p_whh_swz<<<96, 256, 0, stream>>>(wWhhF, swzWF, mode);
    p_whh_swz<<<96, 256, 0, stream>>>(wWhhB, swzWB, mode);
    p_whh_swz<<<96, 256, 0, stream>>>(sWhhF, swzSF, mode);
    p_whh_swz<<<96, 256, 0, stream>>>(sWhhB, swzSB, mode);
    p_cvt<<<256, 256, 0, stream>>>(wWihF, wih_w, 768 * 512, mode);
    p_cvt<<<256, 256, 0, stream>>>(wWihB, wih_w + (size_t)768 * 512, 768 * 512, mode);
    p_cvt<<<256, 256, 0, stream>>>(wLinW, lin_w, 512 * 512, mode);
    p_cvt<<<256, 256, 0, stream>>>(sWihF, swih, 768 * 512, mode);
    p_cvt<<<256, 256, 0, stream>>>(sWihB, swih + (size_t)768 * 512, 768 * 512, mode);
    p_cvt<<<256, 256, 0, stream>>>(sLinW, slin, 512 * 512, mode);
    if (emb_cvt) p_cvt<<<2048, 256, 0, stream>>>(embed_doc, emb_bf, (int)N_EMB, mode);

    const void* embA = emb_cvt ? (const void*)emb_bf : embed_doc;
    const int* amode = emb_cvt ? (mode + 1) : mode;   // mode[1] == 1 (forced bf16)

    // ---- word level, phased over sentence chunks ----
    for (int b0 = 0; b0 < 640; b0 += nb) {
        k_xp_word<<<dim3(nb, 6), 256, 0, stream>>>(embA, batch_doc, wih_w,
                                                   wBihF, wBihB, xp_c, b0, nb, amode, mode);
        k_gru<<<2 * (nb / 16), 256, 0, stream>>>(xp_c, swzWF, swzWB, wBhhF, wBhhB,
                                                 length_sent + b0, enc_c, 64, nb, mode);
        k_att<<<nb, 256, 0, stream>>>(enc_c, lin_w, wLinB, wAttw, att_c, mode);
        k_softsum<<<nb, 256, 0, stream>>>(att_c, enc_c, length_sent + b0,
                                          sent_pad + (size_t)(1 + b0) * 512,
                                          (b0 == 0) ? sent_pad : nullptr, 64, nb);
    }
    // ---- sentence level ----
    k_sent_xp<<<640, 256, 0, stream>>>(sent_order, sent_pad, swih, sBihF, sBihB,
                                       each_sent, xp_s, mode);
    k_gru<<<2, 256, 0, stream>>>(xp_s, swzSF, swzSB, sBhhF, sBhhB,
                                 length_doc, enc_s, 40, 16, mode);
    k_att<<<10, 256, 0, stream>>>(enc_s, slin, sLinB, sAttw, att_s, mode);
    k_softsum<<<16, 256, 0, stream>>>(att_s, enc_s, length_doc, doc_embs, nullptr, 40, 16);
    // ---- scoring ----
    k_final<<<512, 256, 0, stream>>>(men_sent_idx, can_ent_idx, cand_mask, embed_ent,
                                     each_sent, doc_embs, mlpW, mlpB, d_out, mode);
}

// Round 5
// 1559.157 us; speedup vs baseline: 3.8460x; 1.4814x over previous
//
#include <hip/hip_runtime.h>
#include <cstdint>
#include <cstddef>

// ---------------------------------------------------------------------------
// HAN forward on gfx950. Float input dtype (fp32 vs bf16) unknown at build
// time -> probe kernel writes mode flag; prep kernels convert all hot-path
// operands to bf16 once (Whh swizzled into MFMA-fragment order for the 8-wave
// GRU). GRU: 512-thread blocks, h fp32 in registers + hi/lo bf16 LDS mirrors
// (double-buffered, 1 barrier/step), B streamed from L2 with 2-stage pipeline.
// ---------------------------------------------------------------------------

typedef __attribute__((ext_vector_type(8))) short bf16x8;   // 8 bf16 = 4 VGPR
typedef __attribute__((ext_vector_type(4))) float f32x4;

__device__ __forceinline__ float bfraw2f(unsigned int u16) {
    unsigned int x = u16 << 16; float f; __builtin_memcpy(&f, &x, 4); return f;
}
__device__ __forceinline__ unsigned short f2bfraw(float f) {  // RNE
    unsigned int u; __builtin_memcpy(&u, &f, 4);
    unsigned int r = u + 0x7fffu + ((u >> 16) & 1u);
    return (unsigned short)(r >> 16);
}
__device__ __forceinline__ unsigned short f2h(float f) {
    _Float16 h = (_Float16)f; unsigned short u; __builtin_memcpy(&u, &h, 2); return u;
}
__device__ __forceinline__ float h2f(unsigned short u) {
    _Float16 h; __builtin_memcpy(&h, &u, 2); return (float)h;
}
__device__ __forceinline__ float bflo(unsigned int p) {
    unsigned int x = p << 16; float f; __builtin_memcpy(&f, &x, 4); return f;
}
__device__ __forceinline__ float bfhi(unsigned int p) {
    unsigned int x = p & 0xffff0000u; float f; __builtin_memcpy(&f, &x, 4); return f;
}
__device__ __forceinline__ float fast_sigmoid(float x) { return 1.f / (1.f + __expf(-x)); }
__device__ __forceinline__ float fast_tanh(float x) {
    x = fminf(fmaxf(x, -30.f), 30.f);
    float e = __expf(2.f * x);
    return (e - 1.f) / (e + 1.f);
}
__device__ __forceinline__ float fin(float x) {
    return (x == x && fabsf(x) < 1e30f) ? x : 0.f;
}

// ---- dual-mode input adapters (m=1: bf16 u16 buffer, m=0: fp32 buffer) ----
__device__ __forceinline__ float ldsc(const void* p, size_t i, int m) {
    return m ? bfraw2f(((const unsigned short*)p)[i]) : ((const float*)p)[i];
}
__device__ __forceinline__ bf16x8 ld8bf(const void* p, size_t ei, int m) {
    if (m) return *(const bf16x8*)((const unsigned short*)p + ei);
    const float* f = (const float*)p + ei;
    f32x4 a = *(const f32x4*)f, b = *(const f32x4*)(f + 4);
    bf16x8 r;
    r[0] = (short)f2bfraw(a[0]); r[1] = (short)f2bfraw(a[1]);
    r[2] = (short)f2bfraw(a[2]); r[3] = (short)f2bfraw(a[3]);
    r[4] = (short)f2bfraw(b[0]); r[5] = (short)f2bfraw(b[1]);
    r[6] = (short)f2bfraw(b[2]); r[7] = (short)f2bfraw(b[3]);
    return r;
}
__device__ __forceinline__ void ld8f(const void* p, size_t ei, int m, float* o) {
    if (m) {
        uint4 wv = *(const uint4*)((const unsigned short*)p + ei);
        o[0] = bflo(wv.x); o[1] = bfhi(wv.x); o[2] = bflo(wv.y); o[3] = bfhi(wv.y);
        o[4] = bflo(wv.z); o[5] = bfhi(wv.z); o[6] = bflo(wv.w); o[7] = bfhi(wv.w);
    } else {
        const float* f = (const float*)p + ei;
        #pragma unroll
        for (int i = 0; i < 8; ++i) o[i] = f[i];
    }
}

// ---------------------------------------------------------------------------
// K0: dtype probe. flag[0] = mode (1=bf16, 0=fp32); flag[1] = 1 always.
// ---------------------------------------------------------------------------
__global__ void k_probe(const unsigned short* __restrict__ w, int* __restrict__ flag) {
    if (threadIdx.x == 0) {
        int bad = 0;
        for (int i = 0; i < 512; ++i) {
            float v = bfraw2f(w[i]);
            if (!(fabsf(v) <= 1.0f)) bad++;
        }
        flag[0] = (bad == 0) ? 1 : 0;
        flag[1] = 1;
    }
}

// ---------------------------------------------------------------------------
// P1: generic dual-mode -> bf16 convert.
// ---------------------------------------------------------------------------
__global__ void p_cvt(const void* __restrict__ src, unsigned short* __restrict__ dst,
                      int n, const int* __restrict__ modep) {
    const int m = modep[0];
    for (int i = blockIdx.x * 256 + threadIdx.x; i < n; i += gridDim.x * 256)
        dst[i] = f2bfraw(ldsc(src, i, m));
}

// ---------------------------------------------------------------------------
// P2: Whh (768x256) -> bf16 MFMA-fragment order for the 8-wave GRU.
// wave w owns hidden cols [w*32, w*32+32): groups g = reg*2+nt (reg=gate,
// nt=col-tile). Fragment f = (w*6+g)*8+ks, elem addr = f*512 + lane*8 + e.
// Source = whh[(reg*256 + w*32 + nt*16 + lm)*256 + ks*32 + q*8 + e].
// ---------------------------------------------------------------------------
__global__ void p_whh_swz(const void* __restrict__ whh, unsigned short* __restrict__ dst,
                          const int* __restrict__ modep) {
    const int m = modep[0];
    const int idx = blockIdx.x * 256 + threadIdx.x;    // 24576 = 8*6*8*64
    if (idx >= 24576) return;
    const int lane = idx & 63, ks = (idx >> 6) & 7;
    const int g = (idx >> 9) % 6, w = idx / 3072;
    const int lm = lane & 15, q = lane >> 4;
    const int reg = g >> 1, nt = g & 1;
    const int row = reg * 256 + w * 32 + nt * 16 + lm;
    const size_t src = (size_t)row * 256 + ks * 32 + q * 8;
    const size_t d = (size_t)idx * 8;
    #pragma unroll
    for (int e = 0; e < 8; ++e) dst[d + e] = f2bfraw(ldsc(whh, src + e, m));
}

// ---------------------------------------------------------------------------
// K1: gathered word projection. xp[dir][t*nb+bl][768] fp16. grid (nb, 6).
// ---------------------------------------------------------------------------
__global__ __launch_bounds__(256, 2) void k_xp_word(
    const void* __restrict__ embA, const int* __restrict__ batch_doc,
    const unsigned short* __restrict__ wih,       // bf16 [1536][512]
    const void* __restrict__ bih_f, const void* __restrict__ bih_b,
    unsigned short* __restrict__ xp, int b0, int nb,
    const int* __restrict__ amode, const int* __restrict__ modep)
{
    __shared__ unsigned short As[64][40];
    __shared__ unsigned short Bs[256][40];
    const int am = amode[0], m = modep[0];
    const int bm = blockIdx.x, bc = blockIdx.y;
    const int tid = threadIdx.x;
    const int wave = tid >> 6, lane = tid & 63, lm = lane & 15, q = lane >> 4;
    const int arow = tid >> 2, akoff = (tid & 3) * 8;
    const int r = bm * 64 + arow;
    const int tt = r / nb, bl = r - tt * nb;
    const size_t aei = (size_t)batch_doc[(b0 + bl) * 64 + tt] * 512 + akoff;

    const f32x4 fzero = {0.f, 0.f, 0.f, 0.f};
    f32x4 acc[4][4];
    #pragma unroll
    for (int i = 0; i < 4; ++i)
        #pragma unroll
        for (int j = 0; j < 4; ++j) acc[i][j] = fzero;

    for (int kt = 0; kt < 16; ++kt) {
        *(bf16x8*)&As[arow][akoff] = ld8bf(embA, aei + kt * 32, am);
        #pragma unroll
        for (int ld = 0; ld < 4; ++ld) {
            int e = ld * 256 + tid;
            int n = e >> 2, koff = (e & 3) * 8;
            int gn = bc * 256 + n;
            *(uint4*)&Bs[n][koff] = *(const uint4*)(wih + (size_t)gn * 512 + kt * 32 + koff);
        }
        __syncthreads();
        bf16x8 af[4], bv[4];
        #pragma unroll
        for (int mt = 0; mt < 4; ++mt) af[mt] = *(const bf16x8*)&As[mt * 16 + lm][q * 8];
        #pragma unroll
        for (int nt = 0; nt < 4; ++nt) bv[nt] = *(const bf16x8*)&Bs[wave * 64 + nt * 16 + lm][q * 8];
        #pragma unroll
        for (int mt = 0; mt < 4; ++mt)
            #pragma unroll
            for (int nt = 0; nt < 4; ++nt)
                acc[mt][nt] = __builtin_amdgcn_mfma_f32_16x16x32_bf16(af[mt], bv[nt], acc[mt][nt], 0, 0, 0);
        __syncthreads();
    }

    const size_t XPT = (size_t)64 * nb * 768;
    #pragma unroll
    for (int nt = 0; nt < 4; ++nt) {
        const int cn = bc * 256 + wave * 64 + nt * 16 + lm;
        const int dirb = (cn >= 768);
        const int o = cn - dirb * 768;
        const float bias = ldsc(dirb ? bih_b : bih_f, o, m);
        #pragma unroll
        for (int mt = 0; mt < 4; ++mt)
            #pragma unroll
            for (int j = 0; j < 4; ++j) {
                const int rr = bm * 64 + mt * 16 + q * 4 + j;
                xp[(dirb ? XPT : 0) + (size_t)rr * 768 + o] = f2h(acc[mt][nt][j] + bias);
            }
    }
}

// ---------------------------------------------------------------------------
// K2: pipelined GRU. 512 threads (8 waves, 2/SIMD). Wave w owns hidden cols
// [w*32, w*32+32). h fp32 in REGISTERS (lane owns its (s,col) elements);
// hi/lo bf16 mirrors + xp tile in double-buffered LDS -> 1 barrier/step.
// B (swizzled bf16, L2-resident) streamed with 2-stage register pipeline.
// grid = 2*(NB/16), dir = blockIdx&1. xp fp16 [dir][T*NB][768].
// ---------------------------------------------------------------------------
__global__ __launch_bounds__(512, 2) void k_gru(
    const unsigned short* __restrict__ xp,
    const unsigned short* __restrict__ wswz_f,      // bf16 swizzled 196608
    const unsigned short* __restrict__ wswz_b,
    const void* __restrict__ bhh_f, const void* __restrict__ bhh_b,
    const int* __restrict__ lens, float* __restrict__ enc, int T, int NB,
    const int* __restrict__ modep)
{
    __shared__ unsigned short hHi[2][16][264];   // pitch 528B
    __shared__ unsigned short hLo[2][16][264];
    __shared__ unsigned short xpS[2][16][776];   // fp16, pitch 1552B
    __shared__ float bhhS[768];
    __shared__ int lensS[16];
    const int m = modep[0];
    const int tid = threadIdx.x;
    const int w = tid >> 6, lane = tid & 63, lm = lane & 15, q = lane >> 4;
    const int dir = blockIdx.x & 1, sg = blockIdx.x >> 1;
    const int s0 = sg << 4;
    const unsigned short* wsw =
        (dir ? wswz_b : wswz_f) + (size_t)w * 24576 + (size_t)lane * 8;
    const void* bhh = dir ? bhh_b : bhh_f;
    const unsigned short* xpd = xp + (dir ? (size_t)T * NB * 768 : 0);

    for (int e = tid; e < 16 * 264; e += 512) {
        (&hHi[0][0][0])[e] = 0; (&hLo[0][0][0])[e] = 0;
    }
    for (int j = tid; j < 768; j += 512) bhhS[j] = ldsc(bhh, j, m);
    if (tid < 16) lensS[tid] = lens[s0 + tid];

    // prologue: stage xp(t0) into xpS[0]
    {
        const int t0 = dir ? (T - 1) : 0;
        const unsigned short* xrow = xpd + ((size_t)t0 * NB + s0) * 768;
        #pragma unroll
        for (int i = 0; i < 3; ++i) {
            int e = tid + i * 512;                 // [0,1536) dwordx4 slots
            uint4 v = *(const uint4*)(xrow + e * 8);
            *(uint4*)&xpS[0][e / 96][(e % 96) * 8] = v;
        }
    }
    __syncthreads();

    const f32x4 fzero = {0.f, 0.f, 0.f, 0.f};
    float hreg[2][4] = {};                         // h fp32, lane-owned
    uint4 stg[3];
    for (int step = 0; step < T; ++step) {
        const int t = dir ? (T - 1 - step) : step;
        const int cur = step & 1, nxt = cur ^ 1;

        // A fragments from hi/lo mirrors (all waves read all 16 rows)
        bf16x8 ahi[8], alo[8];
        #pragma unroll
        for (int ks = 0; ks < 8; ++ks) {
            ahi[ks] = *(const bf16x8*)&hHi[cur][lm][ks * 32 + q * 8];
            alo[ks] = *(const bf16x8*)&hLo[cur][lm][ks * 32 + q * 8];
        }

        // prefetch next step's xp tile into registers (overlaps MFMA)
        const bool havenext = (step + 1 < T);
        if (havenext) {
            const int tn = dir ? (T - 2 - step) : (step + 1);
            const unsigned short* xrow = xpd + ((size_t)tn * NB + s0) * 768;
            #pragma unroll
            for (int i = 0; i < 3; ++i)
                stg[i] = *(const uint4*)(xrow + (tid + i * 512) * 8);
        }

        // MFMA: 6 groups (reg*2+nt), 2-stage B pipeline
        f32x4 acc[6];
        #pragma unroll
        for (int i = 0; i < 6; ++i) acc[i] = fzero;
        bf16x8 bcur[8], bnxt[8];
        #pragma unroll
        for (int ks = 0; ks < 8; ++ks) bcur[ks] = *(const bf16x8*)(wsw + ks * 512);
        #pragma unroll
        for (int g = 0; g < 6; ++g) {
            if (g < 5) {
                #pragma unroll
                for (int ks = 0; ks < 8; ++ks)
                    bnxt[ks] = *(const bf16x8*)(wsw + ((g + 1) * 8 + ks) * 512);
            }
            #pragma unroll
            for (int ks = 0; ks < 8; ++ks) {
                acc[g] = __builtin_amdgcn_mfma_f32_16x16x32_bf16(ahi[ks], bcur[ks], acc[g], 0, 0, 0);
                acc[g] = __builtin_amdgcn_mfma_f32_16x16x32_bf16(alo[ks], bcur[ks], acc[g], 0, 0, 0);
            }
            #pragma unroll
            for (int ks = 0; ks < 8; ++ks) bcur[ks] = bnxt[ks];
        }

        // gates: lane element (s=q*4+j, col=w*32+nt*16+lm), nt in {0,1}
        #pragma unroll
        for (int nt = 0; nt < 2; ++nt) {
            const int col = w * 32 + nt * 16 + lm;
            const float br = bhhS[col], bz = bhhS[256 + col], bn = bhhS[512 + col];
            #pragma unroll
            for (int j = 0; j < 4; ++j) {
                const int s = q * 4 + j;
                const float xr = h2f(xpS[cur][s][col]);
                const float xz = h2f(xpS[cur][s][256 + col]);
                const float xn = h2f(xpS[cur][s][512 + col]);
                const float rr = fast_sigmoid(xr + acc[nt][j] + br);
                const float zz = fast_sigmoid(xz + acc[2 + nt][j] + bz);
                const float nn = fast_tanh(xn + rr * (acc[4 + nt][j] + bn));
                const float hold = hreg[nt][j];
                float hnew = (1.f - zz) * nn + zz * hold;
                const bool v = (t < lensS[s]);
                hnew = v ? hnew : hold;
                hreg[nt][j] = hnew;
                const unsigned short uh = f2bfraw(hnew);
                hHi[nxt][s][col] = uh;
                hLo[nxt][s][col] = f2bfraw(hnew - bfraw2f(uh));
                enc[((size_t)t * NB + s0 + s) * 512 + (size_t)dir * 256 + col] = v ? hnew : 0.f;
            }
        }

        if (havenext) {    // write prefetched xp tile into the other buffer
            #pragma unroll
            for (int i = 0; i < 3; ++i) {
                int e = tid + i * 512;
                *(uint4*)&xpS[nxt][e / 96][(e % 96) * 8] = stg[i];
            }
        }
        __syncthreads();   // h[nxt] + xpS[nxt] visible for next step
    }
}

// ---------------------------------------------------------------------------
// K3: attention scores, GEMM (M x 512)@(512x512) + fused tanh*attw reduce.
// ---------------------------------------------------------------------------
__global__ __launch_bounds__(256, 1) void k_att(
    const float* __restrict__ enc, const unsigned short* __restrict__ lin_w, // bf16
    const void* __restrict__ lin_b, const void* __restrict__ attw,
    float* __restrict__ att_out, const int* __restrict__ modep)
{
    __shared__ unsigned short As[64][40];
    __shared__ unsigned short Bs[512][40];
    __shared__ float att_part[4][64];
    const int m = modep[0];
    const int bm = blockIdx.x;
    const int tid = threadIdx.x;
    const int wave = tid >> 6, lane = tid & 63, lm = lane & 15, q = lane >> 4;
    const int arow = tid >> 2, akoff = (tid & 3) * 8;
    const float* aptr = enc + (size_t)(bm * 64 + arow) * 512 + akoff;

    const f32x4 fzero = {0.f, 0.f, 0.f, 0.f};
    f32x4 acc[4][8];
    #pragma unroll
    for (int i = 0; i < 4; ++i)
        #pragma unroll
        for (int j = 0; j < 8; ++j) acc[i][j] = fzero;

    for (int kt = 0; kt < 16; ++kt) {
        f32x4 f0 = *(const f32x4*)(aptr + kt * 32);
        f32x4 f1 = *(const f32x4*)(aptr + kt * 32 + 4);
        bf16x8 cv;
        cv[0] = (short)f2bfraw(f0[0]); cv[1] = (short)f2bfraw(f0[1]);
        cv[2] = (short)f2bfraw(f0[2]); cv[3] = (short)f2bfraw(f0[3]);
        cv[4] = (short)f2bfraw(f1[0]); cv[5] = (short)f2bfraw(f1[1]);
        cv[6] = (short)f2bfraw(f1[2]); cv[7] = (short)f2bfraw(f1[3]);
        *(bf16x8*)&As[arow][akoff] = cv;
        #pragma unroll
        for (int ld = 0; ld < 8; ++ld) {
            int e = ld * 256 + tid;
            int n = e >> 2, koff = (e & 3) * 8;
            *(uint4*)&Bs[n][koff] = *(const uint4*)(lin_w + (size_t)n * 512 + kt * 32 + koff);
        }
        __syncthreads();
        bf16x8 af[4];
        #pragma unroll
        for (int mt = 0; mt < 4; ++mt) af[mt] = *(const bf16x8*)&As[mt * 16 + lm][q * 8];
        #pragma unroll
        for (int nt = 0; nt < 8; ++nt) {
            bf16x8 bv = *(const bf16x8*)&Bs[wave * 128 + nt * 16 + lm][q * 8];
            #pragma unroll
            for (int mt = 0; mt < 4; ++mt)
                acc[mt][nt] = __builtin_amdgcn_mfma_f32_16x16x32_bf16(af[mt], bv, acc[mt][nt], 0, 0, 0);
        }
        __syncthreads();
    }

    float part[4][4] = {};
    #pragma unroll
    for (int nt = 0; nt < 8; ++nt) {
        const int col = wave * 128 + nt * 16 + lm;
        const float lb = ldsc(lin_b, col, m);
        const float aw = ldsc(attw, col, m);
        #pragma unroll
        for (int mt = 0; mt < 4; ++mt)
            #pragma unroll
            for (int j = 0; j < 4; ++j)
                part[mt][j] += fast_tanh(acc[mt][nt][j] + lb) * aw;
    }
    #pragma unroll
    for (int mt = 0; mt < 4; ++mt)
        #pragma unroll
        for (int j = 0; j < 4; ++j) {
            float v = part[mt][j];
            #pragma unroll
            for (int d0 = 1; d0 < 16; d0 <<= 1) v += __shfl_xor(v, d0);
            part[mt][j] = v;
        }
    if (lm == 0) {
        #pragma unroll
        for (int mt = 0; mt < 4; ++mt)
            #pragma unroll
            for (int j = 0; j < 4; ++j)
                att_part[wave][mt * 16 + q * 4 + j] = part[mt][j];
    }
    __syncthreads();
    if (tid < 64)
        att_out[(size_t)bm * 64 + tid] =
            att_part[0][tid] + att_part[1][tid] + att_part[2][tid] + att_part[3][tid];
}

// ---------------------------------------------------------------------------
// K4: masked softmax over t + weighted sum of enc rows. grid = NB.
// ---------------------------------------------------------------------------
__global__ __launch_bounds__(256) void k_softsum(
    const float* __restrict__ att, const float* __restrict__ enc,
    const int* __restrict__ lens, float* __restrict__ out,
    float* __restrict__ zero_row, int T, int NB)
{
    __shared__ float eS[64];
    __shared__ float dS;
    const int bb = blockIdx.x, tid = threadIdx.x;
    if (zero_row && bb == 0) { for (int j = tid; j < 512; j += 256) zero_row[j] = 0.f; }
    const int len = lens[bb];
    if (tid < T) {
        float a = fminf(att[(size_t)tid * NB + bb], 50.f);
        eS[tid] = (tid < len) ? __expf(a) : 0.f;
    }
    __syncthreads();
    if (tid == 0) { float s = 0.f; for (int t2 = 0; t2 < T; ++t2) s += eS[t2]; dS = s + 1e-4f; }
    __syncthreads();
    const float inv = 1.f / dS;
    for (int j = tid; j < 512; j += 256) {
        float a0 = 0.f;
        for (int t2 = 0; t2 < T; ++t2) a0 += eS[t2] * enc[((size_t)t2 * NB + bb) * 512 + j];
        out[(size_t)bb * 512 + j] = fin(a0 * inv);
    }
}

// ---------------------------------------------------------------------------
// K5: sentence gather + sentence input projection; writes xp_s fp16.
// ---------------------------------------------------------------------------
__global__ __launch_bounds__(256) void k_sent_xp(
    const int* __restrict__ sent_order, const float* __restrict__ sent_pad,
    const unsigned short* __restrict__ swih,      // bf16 [1536][512]
    const void* __restrict__ bih_f, const void* __restrict__ bih_b,
    float* __restrict__ each_sent, unsigned short* __restrict__ xp_s,
    const int* __restrict__ modep)
{
    __shared__ float aS[512];
    const int m = modep[0];
    const int r = blockIdx.x, tid = threadIdx.x;
    const int idx = sent_order[r];
    const float* src = sent_pad + (size_t)idx * 512;
    for (int j = tid; j < 512; j += 256) { float v = src[j]; aS[j] = v; each_sent[(size_t)r * 512 + j] = v; }
    __syncthreads();
    const int d = r / 40, i2 = r % 40;
    #pragma unroll
    for (int p = 0; p < 6; ++p) {
        const int o = p * 256 + tid;
        const int dirb = (o >= 768);
        const int oo = o - dirb * 768;
        float s = ldsc(dirb ? bih_b : bih_f, oo, m);
        const unsigned short* wrow = swih + (size_t)o * 512;
        for (int k = 0; k < 512; k += 8) {
            const uint4 wv = *(const uint4*)(wrow + k);
            float wf[8];
            wf[0] = bflo(wv.x); wf[1] = bfhi(wv.x); wf[2] = bflo(wv.y); wf[3] = bfhi(wv.y);
            wf[4] = bflo(wv.z); wf[5] = bfhi(wv.z); wf[6] = bflo(wv.w); wf[7] = bfhi(wv.w);
            #pragma unroll
            for (int u = 0; u < 8; ++u) s += aS[k + u] * wf[u];
        }
        xp_s[(size_t)dirb * (40 * 16 * 768) + ((size_t)i2 * 16 + d) * 768 + oo] = f2h(s);
    }
}

// ---------------------------------------------------------------------------
// K6: cosine sims + 64->32 MLP + mask. grid = 512 ((b,m) pairs).
// ---------------------------------------------------------------------------
__global__ __launch_bounds__(256) void k_final(
    const int* __restrict__ men_sent_idx, const int* __restrict__ can_ent_idx,
    const void* __restrict__ cand_mask, const void* __restrict__ embed_ent,
    const float* __restrict__ each_sent, const float* __restrict__ doc_embs,
    const void* __restrict__ mlp_w, const void* __restrict__ mlp_b,
    void* __restrict__ out, const int* __restrict__ modep)
{
    const int bm = blockIdx.x;
    const int b = bm >> 5;
    __shared__ float sv[512], dv[512];
    __shared__ float red[256];
    __shared__ float ssA[32], dsA[32];
    __shared__ float norms[2];
    const int m = modep[0];
    const int tid = threadIdx.x;
    const int sidx = men_sent_idx[bm];
    const float* svp = each_sent + ((size_t)b * 40 + sidx) * 512;
    const float* dvp = doc_embs + (size_t)b * 512;
    float pa = 0.f, pd = 0.f;
    for (int j = tid; j < 512; j += 256) {
        float a = svp[j], d0 = dvp[j];
        sv[j] = a; dv[j] = d0; pa += a * a; pd += d0 * d0;
    }
    red[tid] = pa; __syncthreads();
    for (int s = 128; s > 0; s >>= 1) { if (tid < s) red[tid] += red[tid + s]; __syncthreads(); }
    if (tid == 0) norms[0] = sqrtf(red[0]);
    __syncthreads();
    red[tid] = pd; __syncthreads();
    for (int s = 128; s > 0; s >>= 1) { if (tid < s) red[tid] += red[tid + s]; __syncthreads(); }
    if (tid == 0) norms[1] = sqrtf(red[0]);
    __syncthreads();

    const int c = tid >> 3, jg = tid & 7;
    const int ei = can_ent_idx[(size_t)bm * 32 + c];
    float dsv = 0.f, ddv = 0.f, ne = 0.f;
    for (int k = 0; k < 64; k += 8) {
        float wf[8];
        ld8f(embed_ent, (size_t)ei * 512 + jg * 64 + k, m, wf);
        const int base = jg * 64 + k;
        #pragma unroll
        for (int u = 0; u < 8; ++u) {
            dsv += sv[base + u] * wf[u];
            ddv += dv[base + u] * wf[u];
            ne  += wf[u] * wf[u];
        }
    }
    #pragma unroll
    for (int d0 = 1; d0 < 8; d0 <<= 1) {
        dsv += __shfl_xor(dsv, d0);
        ddv += __shfl_xor(ddv, d0);
        ne  += __shfl_xor(ne, d0);
    }
    if (jg == 0) {
        const float nen = sqrtf(ne);
        const float cm = ldsc(cand_mask, (size_t)bm * 32 + c, m);
        ssA[c] = dsv / fmaxf(norms[0] * nen, 1e-8f) * cm;
        dsA[c] = ddv / fmaxf(norms[1] * nen, 1e-8f) * cm;
    }
    __syncthreads();
    if (tid < 32) {
        float o = ldsc(mlp_b, tid, m);
        for (int j2 = 0; j2 < 32; ++j2) {
            o += ssA[j2] * ldsc(mlp_w, tid * 64 + j2, m);
            o += dsA[j2] * ldsc(mlp_w, tid * 64 + 32 + j2, m);
        }
        const float maskv = (ssA[tid] != 0.f) ? 1.f : 0.f;
        const float v = fin(o * maskv);
        if (m) ((unsigned short*)out)[(size_t)bm * 32 + tid] = f2bfraw(v);
        else   ((float*)out)[(size_t)bm * 32 + tid] = v;
    }
}

// ---------------------------------------------------------------------------
extern "C" void kernel_launch(void* const* d_in, const int* in_sizes, int n_in,
                              void* d_out, int out_size, void* d_ws, size_t ws_size,
                              hipStream_t stream)
{
    (void)in_sizes; (void)n_in; (void)out_size;
    const int* batch_doc    = (const int*)d_in[0];
    const int* sent_order   = (const int*)d_in[1];
    const int* length_sent  = (const int*)d_in[2];
    const int* length_doc   = (const int*)d_in[3];
    const int* men_sent_idx = (const int*)d_in[4];
    const int* can_ent_idx  = (const int*)d_in[5];
    const void* cand_mask = d_in[6];
    const void* embed_doc = d_in[7];
    const void* embed_ent = d_in[8];
    const void* wWihF = d_in[9];
    const void* wWhhF = d_in[10];
    const void* wBihF = d_in[11];
    const void* wBhhF = d_in[12];
    const void* wWihB = d_in[13];
    const void* wWhhB = d_in[14];
    const void* wBihB = d_in[15];
    const void* wBhhB = d_in[16];
    const void* wLinW = d_in[17];
    const void* wLinB = d_in[18];
    const void* wAttw = d_in[19];
    const void* sWihF = d_in[20];
    const void* sWhhF = d_in[21];
    const void* sBihF = d_in[22];
    const void* sBhhF = d_in[23];
    const void* sWihB = d_in[24];
    const void* sWhhB = d_in[25];
    const void* sBihB = d_in[26];
    const void* sBhhB = d_in[27];
    const void* sLinW = d_in[28];
    const void* sLinB = d_in[29];
    const void* sAttw = d_in[30];
    const void* mlpW  = d_in[31];
    const void* mlpB  = d_in[32];

    const size_t N_EMB = (size_t)50000 * 512;
    const size_t FIXED_CORE =
        256 + 4 * (size_t)196608 * 2 +
        (size_t)1536 * 512 * 2 + (size_t)512 * 512 * 2 +
        (size_t)1536 * 512 * 2 + (size_t)512 * 512 * 2 +
        (size_t)328192 * 4 + (size_t)327680 * 4 + (size_t)983040 * 2 +
        (size_t)327680 * 4 + (size_t)640 * 4 + (size_t)8192 * 4 + 65536;
    auto need = [&](int nb, int emb) -> size_t {
        return FIXED_CORE + (size_t)nb * (196608 + 131072 + 256)
             + (emb ? N_EMB * 2 : 0) + (1u << 20);
    };
    int emb_cvt = 1, nb = 320;
    {
        const int ladder[6] = {640, 320, 160, 80, 40, 16};
        bool found = false;
        for (int e = 1; e >= 0 && !found; --e)
            for (int i = 0; i < 6 && !found; ++i)
                if (need(ladder[i], e) <= ws_size) { emb_cvt = e; nb = ladder[i]; found = true; }
    }

    char* base = (char*)d_ws;
    size_t off = 0;
    auto take = [&](size_t bytes) -> void* {
        void* p = base + off; off += (bytes + 255) & ~(size_t)255; return p;
    };
    int* mode = (int*)take(256);
    unsigned short* swzWF = (unsigned short*)take((size_t)196608 * 2);
    unsigned short* swzWB = (unsigned short*)take((size_t)196608 * 2);
    unsigned short* swzSF = (unsigned short*)take((size_t)196608 * 2);
    unsigned short* swzSB = (unsigned short*)take((size_t)196608 * 2);
    unsigned short* wih_w = (unsigned short*)take((size_t)1536 * 512 * 2);
    unsigned short* lin_w = (unsigned short*)take((size_t)512 * 512 * 2);
    unsigned short* swih  = (unsigned short*)take((size_t)1536 * 512 * 2);
    unsigned short* slin  = (unsigned short*)take((size_t)512 * 512 * 2);
    float* sent_pad  = (float*)take((size_t)328192 * 4);
    float* each_sent = (float*)take((size_t)327680 * 4);
    unsigned short* xp_s = (unsigned short*)take((size_t)983040 * 2);
    float* enc_s     = (float*)take((size_t)327680 * 4);
    float* att_s     = (float*)take((size_t)640 * 4);
    float* doc_embs  = (float*)take((size_t)8192 * 4);
    unsigned short* xp_c = (unsigned short*)take((size_t)nb * 196608);
    float* enc_c     = (float*)take((size_t)nb * 131072);
    float* att_c     = (float*)take((size_t)nb * 256);
    unsigned short* emb_bf = emb_cvt ? (unsigned short*)take(N_EMB * 2) : nullptr;

    // ---- probe + prep ----
    k_probe<<<1, 64, 0, stream>>>((const unsigned short*)wWhhF, mode);
    p_whh_swz<<<96, 256, 0, stream>>>(wWhhF, swzWF, mode);
    p_whh_swz<<<96, 256, 0, stream>>>(wWhhB, swzWB, mode);
    p_whh_swz<<<96, 256, 0, stream>>>(sWhhF, swzSF, mode);
    p_whh_swz<<<96, 256, 0, stream>>>(sWhhB, swzSB, mode);
    p_cvt<<<256, 256, 0, stream>>>(wWihF, wih_w, 768 * 512, mode);
    p_cvt<<<256, 256, 0, stream>>>(wWihB, wih_w + (size_t)768 * 512, 768 * 512, mode);
    p_cvt<<<256, 256, 0, stream>>>(wLinW, lin_w, 512 * 512, mode);
    p_cvt<<<256, 256, 0, stream>>>(sWihF, swih, 768 * 512, mode);
    p_cvt<<<256, 256, 0, stream>>>(sWihB, swih + (size_t)768 * 512, 768 * 512, mode);
    p_cvt<<<256, 256, 0, stream>>>(sLinW, slin, 512 * 512, mode);
    if (emb_cvt) p_cvt<<<2048, 256, 0, stream>>>(embed_doc, emb_bf, (int)N_EMB, mode);

    const void* embA = emb_cvt ? (const void*)emb_bf : embed_doc;
    const int* amode = emb_cvt ? (mode + 1) : mode;

    // ---- word level, phased over sentence chunks ----
    for (int b0 = 0; b0 < 640; b0 += nb) {
        k_xp_word<<<dim3(nb, 6), 256, 0, stream>>>(embA, batch_doc, wih_w,
                                                   wBihF, wBihB, xp_c, b0, nb, amode, mode);
        k_gru<<<2 * (nb / 16), 512, 0, stream>>>(xp_c, swzWF, swzWB, wBhhF, wBhhB,
                                                 length_sent + b0, enc_c, 64, nb, mode);
        k_att<<<nb, 256, 0, stream>>>(enc_c, lin_w, wLinB, wAttw, att_c, mode);
        k_softsum<<<nb, 256, 0, stream>>>(att_c, enc_c, length_sent + b0,
                                          sent_pad + (size_t)(1 + b0) * 512,
                                          (b0 == 0) ? sent_pad : nullptr, 64, nb);
    }
    // ---- sentence level ----
    k_sent_xp<<<640, 256, 0, stream>>>(sent_order, sent_pad, swih, sBihF, sBihB,
                                       each_sent, xp_s, mode);
    k_gru<<<2, 512, 0, stream>>>(xp_s, swzSF, swzSB, sBhhF, sBhhB,
                                 length_doc, enc_s, 40, 16, mode);
    k_att<<<10, 256, 0, stream>>>(enc_s, slin, sLinB, sAttw, att_s, mode);
    k_softsum<<<16, 256, 0, stream>>>(att_s, enc_s, length_doc, doc_embs, nullptr, 40, 16);
    // ---- scoring ----
    k_final<<<512, 256, 0, stream>>>(men_sent_idx, can_ent_idx, cand_mask, embed_ent,
                                     each_sent, doc_embs, mlpW, mlpB, d_out, mode);
}